// Round 17
// baseline (737.401 us; speedup 1.0000x reference)
//
#include <hip/hip_runtime.h>
#include <cstdint>

typedef unsigned short ushort_t;
typedef _Float16 half_t;
typedef __attribute__((ext_vector_type(8))) short short8;
typedef __attribute__((ext_vector_type(8))) half_t half8;
typedef __attribute__((ext_vector_type(4))) float f32x4;

// ---------------- helpers ----------------
__device__ __forceinline__ void gld_lds16(const ushort_t* g, ushort_t* l) {
    __builtin_amdgcn_global_load_lds((const __attribute__((address_space(1))) void*)g,
                                     (__attribute__((address_space(3))) void*)l,
                                     16, 0, 0);
}

// spline/silu expansion of one scalar -> 9 plane values (shared by expand kernels + flash epilogue)
__device__ __forceinline__ void expand9(float x, float* w9) {
    float si = x / (1.0f + __expf(-x));
    float u = (x + 2.2f) * 2.5f;
    int ji = (int)floorf(u);
    float f = u - (float)ji;
    if (!(ji >= 0 && ji <= 10)) ji = -100;      // outside knot range -> all bases 0
    float f2 = f * f, f3 = f2 * f;
    float w_i   = f3 * (1.0f / 6.0f);
    float w_im1 = (1.0f + 3.0f * f + 3.0f * f2 - 3.0f * f3) * (1.0f/6.0f);
    float w_im2 = (4.0f - 6.0f * f2 + 3.0f * f3) * (1.0f/6.0f);
    float omf = 1.0f - f;
    float w_im3 = omf * omf * omf * (1.0f / 6.0f);
    w9[0] = si;
    #pragma unroll
    for (int c = 0; c < 8; ++c) {
        float v = 0.0f;
        v = (c == ji    ) ? w_i   : v;
        v = (c == ji - 1) ? w_im1 : v;
        v = (c == ji - 2) ? w_im2 : v;
        v = (c == ji - 3) ? w_im3 : v;
        w9[c + 1] = v;
    }
}

// ---------------- expand: X fp32 [N][IN] -> E fp16 [N][9][IN] ----------------
template<int IN>
__global__ void expand_kernel(const float* __restrict__ X, half_t* __restrict__ E, int nrows) {
    int idx = blockIdx.x * 256 + threadIdx.x;
    if (idx >= nrows * IN) return;
    int n = idx / IN, i = idx % IN;
    float w9[9];
    expand9(X[idx], w9);
    half_t* Er = E + (long)n * 9 * IN + i;
    #pragma unroll
    for (int c = 0; c < 9; ++c) Er[(long)c * IN] = (half_t)w9[c];
}

// ---------------- fused weight pack: all six layers in one launch ----------------
// layout per layer: [o][9][IN] fp16; lo-planes only for k1/k2 (q/k/v/o are hi-only in GEMM).
__global__ void pack_all(const float* __restrict__ k1b, const float* __restrict__ k1s,
                         const float* __restrict__ k2b, const float* __restrict__ k2s,
                         const float* __restrict__ qb,  const float* __restrict__ qs,
                         const float* __restrict__ kb,  const float* __restrict__ ks_,
                         const float* __restrict__ vb,  const float* __restrict__ vs,
                         const float* __restrict__ ob,  const float* __restrict__ os_,
                         half_t* __restrict__ W1hi, half_t* __restrict__ W1lo,
                         half_t* __restrict__ W2hi, half_t* __restrict__ W2lo,
                         half_t* __restrict__ Wqhi, half_t* __restrict__ Wohi) {
    int idx = blockIdx.x * 256 + threadIdx.x;   // 0 .. 2097152
    const float* base; const float* spline; half_t* Whi; half_t* Wlo; int IN; int li;
    if (idx < 524288)       { base = k1b; spline = k1s; Whi = W1hi; Wlo = W1lo; IN = 512;  li = idx; }
    else if (idx < 1048576) { base = k2b; spline = k2s; Whi = W2hi; Wlo = W2lo; IN = 1024; li = idx - 524288; }
    else if (idx < 1310720) { base = qb;  spline = qs;  Whi = Wqhi;                      Wlo = nullptr; IN = 512; li = idx - 1048576; }
    else if (idx < 1572864) { base = kb;  spline = ks_; Whi = Wqhi + (size_t)512 * 4608; Wlo = nullptr; IN = 512; li = idx - 1310720; }
    else if (idx < 1835008) { base = vb;  spline = vs;  Whi = Wqhi + (size_t)1024 * 4608; Wlo = nullptr; IN = 512; li = idx - 1572864; }
    else                    { base = ob;  spline = os_; Whi = Wohi; Wlo = nullptr; IN = 512; li = idx - 1835008; }
    int o = li / IN, i = li % IN;
    long r0 = (long)o * 9 * IN + i;
    long widx = (long)o * IN + i;
    float w[9];
    w[0] = base[widx];
    const f32x4* sp = (const f32x4*)(spline + widx * 8);
    f32x4 s0 = sp[0], s1 = sp[1];
    w[1] = s0[0]; w[2] = s0[1]; w[3] = s0[2]; w[4] = s0[3];
    w[5] = s1[0]; w[6] = s1[1]; w[7] = s1[2]; w[8] = s1[3];
    #pragma unroll
    for (int c = 0; c < 9; ++c) {
        half_t hi = (half_t)w[c];
        Whi[r0 + (long)c * IN] = hi;
        if (Wlo) Wlo[r0 + (long)c * IN] = (half_t)(w[c] - (float)hi);
    }
}

enum { EPI_PART = 0, EPI_QKV = 1, EPI_RELU = 4 };

// ---------------- weight GEMM: r6-proven 2-barrier structure (875 TF measured r13) ----------------
// 128x128 tile, 4 waves (2x2), BK=64, 32 KB LDS -> 5 blocks/CU co-resident (m114 wave overlap).
// + r7-verified swizzle chunk^(row&7) on BOTH global source and ds_read (conflict-free, rule #21).
// Virtual tiles: NPASS==2 -> hi sweep then lo sweep (2*NT); NPASS==1 -> hi only.
// KSPLIT>1 slices the virtual range across blockIdx.z -> fp32 partials P[z].
template<int EPI, int NPASS, int KSPLIT>
__global__ __launch_bounds__(256, 4)
void gemm_w(const ushort_t* __restrict__ A, const ushort_t* __restrict__ Bhi,
            const ushort_t* __restrict__ Blo, float* __restrict__ Cf, float* __restrict__ P,
            half_t* __restrict__ Qp, half_t* __restrict__ Kp, half_t* __restrict__ Vp,
            int M, int N, int K) {
    __shared__ __attribute__((aligned(16))) ushort_t As[128 * 64];
    __shared__ __attribute__((aligned(16))) ushort_t Bs[128 * 64];
    const int tid = threadIdx.x;
    const int lane = tid & 63;
    const int wave = tid >> 6;
    const int wm = wave >> 1, wn = wave & 1;
    const int bm = blockIdx.x * 128, bn = blockIdx.y * 128;
    const int l15 = lane & 15, l16 = lane >> 4;
    const int NT = K >> 6;
    const int TV = (NPASS == 2) ? 2 * NT : NT;
    int kc, t0;
    if constexpr (KSPLIT > 1) { kc = TV / KSPLIT; t0 = blockIdx.z * kc; }
    else { kc = TV; t0 = 0; }

    f32x4 acc[4][4];
    #pragma unroll
    for (int m = 0; m < 4; ++m)
        #pragma unroll
        for (int n = 0; n < 4; ++n) acc[m][n] = (f32x4){0.f, 0.f, 0.f, 0.f};

    for (int u = 0; u < kc; ++u) {
        int tt = t0 + u;
        int pass = (tt >= NT) ? 1 : 0;
        int kt = (tt - (pass ? NT : 0)) << 6;
        const ushort_t* Bb = pass ? Blo : Bhi;
        #pragma unroll
        for (int r = 0; r < 4; ++r) {
            int ch = r * 256 + tid;             // 1024 chunks of 8 halves per 128x64 tile
            int row = ch >> 3, c = ch & 7;
            gld_lds16(A + (long)(bm + row) * K + kt + ((c ^ (row & 7)) << 3), &As[ch * 8]);
        }
        #pragma unroll
        for (int r = 0; r < 4; ++r) {
            int ch = r * 256 + tid;
            int row = ch >> 3, c = ch & 7;
            gld_lds16(Bb + (long)(bn + row) * K + kt + ((c ^ (row & 7)) << 3), &Bs[ch * 8]);
        }
        __syncthreads();
        #pragma unroll
        for (int kk = 0; kk < 2; ++kk) {
            half8 af[4], bfr[4];
            #pragma unroll
            for (int m = 0; m < 4; ++m) {
                int row = wm * 64 + m * 16 + l15;
                af[m] = __builtin_bit_cast(half8, *(const short8*)&As[row * 64 + (((kk * 4 + l16) ^ (row & 7)) << 3)]);
            }
            #pragma unroll
            for (int n = 0; n < 4; ++n) {
                int row = wn * 64 + n * 16 + l15;
                bfr[n] = __builtin_bit_cast(half8, *(const short8*)&Bs[row * 64 + (((kk * 4 + l16) ^ (row & 7)) << 3)]);
            }
            #pragma unroll
            for (int m = 0; m < 4; ++m)
                #pragma unroll
                for (int n = 0; n < 4; ++n)
                    acc[m][n] = __builtin_amdgcn_mfma_f32_16x16x32_f16(af[m], bfr[n], acc[m][n], 0, 0, 0);
        }
        __syncthreads();
    }

    // epilogue: C/D layout col=lane&15, row=(lane>>4)*4+j (m89-verified)
    #pragma unroll
    for (int m = 0; m < 4; ++m) {
        #pragma unroll
        for (int n = 0; n < 4; ++n) {
            #pragma unroll
            for (int j = 0; j < 4; ++j) {
                int row = bm + wm * 64 + m * 16 + l16 * 4 + j;
                int col = bn + wn * 64 + n * 16 + l15;
                float v = acc[m][n][j];
                if constexpr (KSPLIT > 1) {
                    P[(size_t)blockIdx.z * M * N + (long)row * N + col] = v;
                } else if constexpr (EPI == EPI_RELU) {
                    Cf[(long)row * N + col] = fmaxf(v, 0.0f);
                } else if constexpr (EPI == EPI_QKV) {
                    int which = col >> 9, w5 = col & 511, h = w5 >> 7, d = w5 & 127;
                    int b = row >> 10, ss = row & 1023;
                    half_t* dst = (which == 0) ? Qp : ((which == 1) ? Kp : Vp);
                    dst[(((long)(b * 4 + h) * 1024 + ss) << 7) + d] = (half_t)v;
                }
            }
        }
    }
}

// ---------------- fused flash attention + E4 expansion ----------------
// grid (8 q-tiles, 32 bh), 256 threads = 4 waves row-split (softmax rows wave-local;
// reduce = shfl_xor over l15). Q register-resident. Swizzle chunk^(row&15) on gld source,
// ds_read and Ps writes (rule #21). Epilogue expands o=O/l into E4 [row][9][512] directly.
__global__ __launch_bounds__(256, 1)
void flash_attn(const ushort_t* __restrict__ Q, const ushort_t* __restrict__ Kb,
                const ushort_t* __restrict__ Vt, half_t* __restrict__ E4, float scale) {
    constexpr int TS = 128 * 128;
    __shared__ __attribute__((aligned(16))) ushort_t Qs[TS];
    __shared__ __attribute__((aligned(16))) ushort_t Ks[TS];
    __shared__ __attribute__((aligned(16))) ushort_t Vs[TS];
    __shared__ __attribute__((aligned(16))) half_t  Ps[TS];
    const int tid = threadIdx.x;
    const int lane = tid & 63;
    const int w = tid >> 6;                    // wave 0..3 -> q-rows [w*32, w*32+32)
    const int l15 = lane & 15, l16 = lane >> 4;
    const int bm = blockIdx.x * 128;
    const int bh = blockIdx.y;
    const ushort_t* Qg = Q + (long)bh * 1024 * 128;
    const ushort_t* Kg = Kb + (long)bh * 1024 * 128;
    const ushort_t* Vg = Vt + (long)bh * 128 * 1024;

    #pragma unroll
    for (int r = 0; r < 8; ++r) {
        int ch = r * 256 + tid;
        int row = ch >> 4, c = ch & 15;
        gld_lds16(Qg + (long)(bm + row) * 128 + ((c ^ (row & 15)) << 3), &Qs[ch * 8]);
    }
    __syncthreads();
    half8 qf[2][4];
    #pragma unroll
    for (int mf = 0; mf < 2; ++mf)
        #pragma unroll
        for (int kk = 0; kk < 4; ++kk) {
            int row = w * 32 + mf * 16 + l15;
            qf[mf][kk] = __builtin_bit_cast(half8, *(const short8*)&Qs[row * 128 + (((kk * 4 + l16) ^ (row & 15)) << 3)]);
        }

    f32x4 o_acc[2][8];
    #pragma unroll
    for (int mf = 0; mf < 2; ++mf)
        #pragma unroll
        for (int nf = 0; nf < 8; ++nf) o_acc[mf][nf] = (f32x4){0.f, 0.f, 0.f, 0.f};
    float m_run[2][4], l_run[2][4];
    #pragma unroll
    for (int mf = 0; mf < 2; ++mf)
        #pragma unroll
        for (int j = 0; j < 4; ++j) { m_run[mf][j] = -3.0e38f; l_run[mf][j] = 0.f; }

    for (int t = 0; t < 8; ++t) {
        int kv0 = t * 128;
        #pragma unroll
        for (int r = 0; r < 8; ++r) {
            int ch = r * 256 + tid;
            int row = ch >> 4, c = ch & 15;
            gld_lds16(Kg + (long)(kv0 + row) * 128 + ((c ^ (row & 15)) << 3), &Ks[ch * 8]);
        }
        #pragma unroll
        for (int r = 0; r < 8; ++r) {
            int ch = r * 256 + tid;
            int row = ch >> 4, c = ch & 15;    // row = d
            gld_lds16(Vg + (long)row * 1024 + kv0 + ((c ^ (row & 15)) << 3), (ushort_t*)&Vs[ch * 8]);
        }
        __syncthreads();
        f32x4 s_acc[2][8];
        #pragma unroll
        for (int mf = 0; mf < 2; ++mf)
            #pragma unroll
            for (int nf = 0; nf < 8; ++nf) s_acc[mf][nf] = (f32x4){0.f, 0.f, 0.f, 0.f};
        #pragma unroll
        for (int nf = 0; nf < 8; ++nf) {
            #pragma unroll
            for (int kk = 0; kk < 4; ++kk) {
                int row = nf * 16 + l15;
                half8 bf = __builtin_bit_cast(half8, *(const short8*)&Ks[row * 128 + (((kk * 4 + l16) ^ (row & 15)) << 3)]);
                #pragma unroll
                for (int mf = 0; mf < 2; ++mf)
                    s_acc[mf][nf] = __builtin_amdgcn_mfma_f32_16x16x32_f16(qf[mf][kk], bf, s_acc[mf][nf], 0, 0, 0);
            }
        }
        #pragma unroll
        for (int mf = 0; mf < 2; ++mf) {
            #pragma unroll
            for (int j = 0; j < 4; ++j) {
                float rmax = -3.0e38f;
                #pragma unroll
                for (int nf = 0; nf < 8; ++nf) rmax = fmaxf(rmax, s_acc[mf][nf][j]);
                #pragma unroll
                for (int off = 1; off < 16; off <<= 1) rmax = fmaxf(rmax, __shfl_xor(rmax, off));
                float m_new = fmaxf(m_run[mf][j], rmax * scale);
                float alpha = __expf(m_run[mf][j] - m_new);
                m_run[mf][j] = m_new;
                float rsum = 0.f;
                #pragma unroll
                for (int nf = 0; nf < 8; ++nf) {
                    float pv = __expf(s_acc[mf][nf][j] * scale - m_new);
                    s_acc[mf][nf][j] = pv;
                    rsum += pv;
                }
                #pragma unroll
                for (int off = 1; off < 16; off <<= 1) rsum += __shfl_xor(rsum, off);
                l_run[mf][j] = l_run[mf][j] * alpha + rsum;
                #pragma unroll
                for (int nf = 0; nf < 8; ++nf) o_acc[mf][nf][j] *= alpha;
            }
        }
        #pragma unroll
        for (int mf = 0; mf < 2; ++mf)
            #pragma unroll
            for (int nf = 0; nf < 8; ++nf)
                #pragma unroll
                for (int j = 0; j < 4; ++j) {
                    int row = w * 32 + mf * 16 + l16 * 4 + j;
                    int col = nf * 16 + l15;
                    int sch = (col >> 3) ^ (row & 15);
                    Ps[row * 128 + (sch << 3) + (col & 7)] = (half_t)s_acc[mf][nf][j];
                }
        __syncthreads();
        half8 pf[2][4];
        #pragma unroll
        for (int mf = 0; mf < 2; ++mf)
            #pragma unroll
            for (int kk = 0; kk < 4; ++kk) {
                int row = w * 32 + mf * 16 + l15;
                pf[mf][kk] = __builtin_bit_cast(half8, *(const short8*)&Ps[row * 128 + (((kk * 4 + l16) ^ (row & 15)) << 3)]);
            }
        #pragma unroll
        for (int nf = 0; nf < 8; ++nf) {
            #pragma unroll
            for (int kk = 0; kk < 4; ++kk) {
                int row = nf * 16 + l15;       // d
                half8 bf = __builtin_bit_cast(half8, *(const short8*)&Vs[row * 128 + (((kk * 4 + l16) ^ (row & 15)) << 3)]);
                #pragma unroll
                for (int mf = 0; mf < 2; ++mf)
                    o_acc[mf][nf] = __builtin_amdgcn_mfma_f32_16x16x32_f16(pf[mf][kk], bf, o_acc[mf][nf], 0, 0, 0);
            }
        }
        __syncthreads();
    }
    // epilogue: o = O/l, expand to 9 planes, write E4 [row][9][512] at col h*128+d
    int b = bh >> 2, h = bh & 3;
    #pragma unroll
    for (int mf = 0; mf < 2; ++mf) {
        #pragma unroll
        for (int nf = 0; nf < 8; ++nf) {
            #pragma unroll
            for (int j = 0; j < 4; ++j) {
                int srow = bm + w * 32 + mf * 16 + l16 * 4 + j;
                int col = h * 128 + nf * 16 + l15;
                float o = o_acc[mf][nf][j] / l_run[mf][j];
                float w9[9];
                expand9(o, w9);
                half_t* Er = E4 + (long)(b * 1024 + srow) * 4608 + col;
                #pragma unroll
                for (int c = 0; c < 9; ++c) Er[(long)c * 512] = (half_t)w9[c];
            }
        }
    }
}

// ---------------- split-K reduction ----------------
template<int KS, bool RELU>
__global__ void reduce_kernel(const float* __restrict__ P, float* __restrict__ out, long MN) {
    long i = ((long)blockIdx.x * 256 + threadIdx.x) * 4;
    if (i >= MN) return;
    f32x4 s = *(const f32x4*)&P[i];
    #pragma unroll
    for (int zz = 1; zz < KS; ++zz) {
        f32x4 t = *(const f32x4*)&P[(size_t)zz * MN + i];
        s += t;
    }
    if constexpr (RELU) {
        s[0] = fmaxf(s[0], 0.f); s[1] = fmaxf(s[1], 0.f);
        s[2] = fmaxf(s[2], 0.f); s[3] = fmaxf(s[3], 0.f);
    }
    *(f32x4*)&out[i] = s;
}

// ---------------- V transpose ----------------
__global__ void transpose_v(const ushort_t* __restrict__ V, ushort_t* __restrict__ Vt) {
    __shared__ ushort_t t[64][72];
    int s0 = blockIdx.x * 64, d0 = blockIdx.y * 64, bh = blockIdx.z;
    const ushort_t* Vb = V + (long)bh * 1024 * 128;
    ushort_t* Vtb = Vt + (long)bh * 128 * 1024;
    int tid = threadIdx.x;
    int r = tid >> 2, g = tid & 3;
    #pragma unroll
    for (int j = 0; j < 16; ++j)
        t[r][g * 16 + j] = Vb[(long)(s0 + r) * 128 + d0 + g * 16 + j];
    __syncthreads();
    #pragma unroll
    for (int j = 0; j < 16; ++j)
        Vtb[(long)(d0 + r) * 1024 + s0 + g * 16 + j] = t[g * 16 + j][r];
}

// ---------------- fused split-K2 reduce + residual + LayerNorm (rows of 512) ----------------
__global__ void reduce2_ln_kernel(const float* __restrict__ P, long MN,
                                  const float* __restrict__ X,
                                  const float* __restrict__ g, const float* __restrict__ b,
                                  float* __restrict__ out) {
    long row = (long)blockIdx.x * 4 + (threadIdx.x >> 6);
    int lane = threadIdx.x & 63;
    long base = row * 512 + lane * 8;
    f32x4 p0 = *(const f32x4*)&P[base],      p1 = *(const f32x4*)&P[base + 4];
    f32x4 q0 = *(const f32x4*)&P[MN + base], q1 = *(const f32x4*)&P[MN + base + 4];
    f32x4 x0 = *(const f32x4*)&X[base],      x1 = *(const f32x4*)&X[base + 4];
    float y[8];
    #pragma unroll
    for (int j = 0; j < 4; ++j) {
        y[j]     = (p0[j] + q0[j]) + x0[j];
        y[j + 4] = (p1[j] + q1[j]) + x1[j];
    }
    float s = 0.f;
    #pragma unroll
    for (int j = 0; j < 8; ++j) s += y[j];
    #pragma unroll
    for (int off = 32; off > 0; off >>= 1) s += __shfl_xor(s, off);
    float mu = s * (1.0f / 512.0f);
    float vs = 0.f;
    #pragma unroll
    for (int j = 0; j < 8; ++j) { float d = y[j] - mu; vs += d * d; }
    #pragma unroll
    for (int off = 32; off > 0; off >>= 1) vs += __shfl_xor(vs, off);
    float r = rsqrtf(vs * (1.0f / 512.0f) + 1e-5f);
    f32x4 w0 = *(const f32x4*)&g[lane * 8], w1 = *(const f32x4*)&g[lane * 8 + 4];
    f32x4 b0 = *(const f32x4*)&b[lane * 8], b1 = *(const f32x4*)&b[lane * 8 + 4];
    f32x4 r0, r1;
    #pragma unroll
    for (int j = 0; j < 4; ++j) {
        r0[j] = (y[j] - mu) * r * w0[j] + b0[j];
        r1[j] = (y[j + 4] - mu) * r * w1[j] + b1[j];
    }
    *(f32x4*)&out[base] = r0;
    *(f32x4*)&out[base + 4] = r1;
}

// ---------------- launch ----------------
extern "C" void kernel_launch(void* const* d_in, const int* in_sizes, int n_in,
                              void* d_out, int out_size, void* d_ws, size_t ws_size,
                              hipStream_t stream) {
    const float* x         = (const float*)d_in[0];
    const float* k1_base   = (const float*)d_in[1];
    const float* k1_spline = (const float*)d_in[2];
    const float* k2_base   = (const float*)d_in[3];
    const float* k2_spline = (const float*)d_in[4];
    const float* q_base    = (const float*)d_in[5];
    const float* q_spline  = (const float*)d_in[6];
    const float* k_base    = (const float*)d_in[7];
    const float* k_spline  = (const float*)d_in[8];
    const float* v_base    = (const float*)d_in[9];
    const float* v_spline  = (const float*)d_in[10];
    const float* o_base    = (const float*)d_in[11];
    const float* o_spline  = (const float*)d_in[12];
    const float* ln_w      = (const float*)d_in[13];
    const float* ln_b      = (const float*)d_in[14];
    float* out = (float*)d_out;

    constexpr int Dm = 512, HD = 1024, NR = 8192;
    constexpr int K1 = 9 * Dm;   // 4608
    constexpr int K2 = 9 * HD;   // 9216
    constexpr size_t MB = 1024 * 1024;

    char* p = (char*)d_ws;
    size_t off = 0;
    auto take = [&](size_t bytes) -> char* {
        char* r = p + off;
        off += (bytes + 255) & ~(size_t)255;
        return r;
    };
    half_t* W1hi = (half_t*)take((size_t)HD * K1 * 2);        //  9 MB
    half_t* W2hi = (half_t*)take((size_t)Dm * K2 * 2);        //  9 MB
    half_t* Wqhi = (half_t*)take((size_t)3 * Dm * K1 * 2);    // 13.5 MB
    half_t* Wohi = (half_t*)take((size_t)Dm * K1 * 2);        //  4.5 MB
    half_t* W1lo = (half_t*)take((size_t)HD * K1 * 2);
    half_t* W2lo = (half_t*)take((size_t)Dm * K2 * 2);
    char*   A    = take((size_t)152 * MB);                    // total 206 MB (< 224 proven-safe)
    (void)ws_size; (void)in_sizes; (void)n_in; (void)out_size;

    // arena phase map (MB):
    // A: E1 @0..72 | H1 fp32 @72..104 (direct ReLU epilogue)
    // B: E2c @0..72 | H1 @72..104 | P2 @104..136 (4x8) | H2 @136..152
    // C: E3 @0..72 | Q @72..80 K @80..88 V @88..96 | H2 @136..152
    // D: Vt @96..104 (V dead) | flash: reads Q/K/Vt, writes E4 @0..72 (E3 dead)
    // E: O-proj reads E4 @0..72 | P3 @120..152 (2x16) | fused reduce2+LN reads P3
    half_t* E1   = (half_t*)(A);
    float*  H1   = (float*)(A + 72 * MB);
    half_t* E2   = (half_t*)(A);
    float*  P2   = (float*)(A + 104 * MB);
    float*  H2   = (float*)(A + 136 * MB);
    half_t* E3   = (half_t*)(A);
    half_t* Qb   = (half_t*)(A + 72 * MB);
    half_t* Kb   = (half_t*)(A + 80 * MB);
    half_t* Vb   = (half_t*)(A + 88 * MB);
    half_t* Vt   = (half_t*)(A + 96 * MB);
    half_t* E4   = (half_t*)(A);
    float*  P3   = (float*)(A + 120 * MB);

    // single fused pack launch (2M elements); q/k/v/o layers are hi-only
    pack_all<<<2097152 / 256, 256, 0, stream>>>(
        k1_base, k1_spline, k2_base, k2_spline, q_base, q_spline,
        k_base, k_spline, v_base, v_spline, o_base, o_spline,
        W1hi, W1lo, W2hi, W2lo, Wqhi, Wohi);

    // KAN1: hi+lo serial, direct ReLU epilogue, grid 64x8 = 512
    expand_kernel<Dm><<<(NR * Dm) / 256, 256, 0, stream>>>(x, E1, NR);
    gemm_w<EPI_RELU, 2, 1><<<dim3(NR / 128, HD / 128, 1), 256, 0, stream>>>(
        (const ushort_t*)E1, (const ushort_t*)W1hi, (const ushort_t*)W1lo,
        H1, nullptr, nullptr, nullptr, nullptr, NR, HD, K1);

    // KAN2 (2 M-chunks, hi+lo, KSPLIT=4): grid 32x4x4 = 512
    for (int c = 0; c < 2; ++c) {
        expand_kernel<HD><<<(4096 * HD) / 256, 256, 0, stream>>>(H1 + (size_t)c * 4096 * HD, E2, 4096);
        gemm_w<EPI_PART, 2, 4><<<dim3(4096 / 128, Dm / 128, 4), 256, 0, stream>>>(
            (const ushort_t*)E2, (const ushort_t*)W2hi, (const ushort_t*)W2lo,
            nullptr, P2, nullptr, nullptr, nullptr, 4096, Dm, K2);
        reduce_kernel<4, false><<<(4096 * Dm) / 1024, 256, 0, stream>>>(P2, H2 + (size_t)c * 4096 * Dm, (long)4096 * Dm);
    }

    // QKV: hi-only single pass, direct scatter, grid 64x12 = 768 (3/CU)
    expand_kernel<Dm><<<(NR * Dm) / 256, 256, 0, stream>>>(H2, E3, NR);
    gemm_w<EPI_QKV, 1, 1><<<dim3(NR / 128, (3 * Dm) / 128, 1), 256, 0, stream>>>(
        (const ushort_t*)E3, (const ushort_t*)Wqhi, nullptr,
        nullptr, nullptr, Qb, Kb, Vb, NR, 3 * Dm, K1);

    // attention: Vt transpose; fused flash (+ E4 expansion epilogue), grid 8x32 = 256
    transpose_v<<<dim3(16, 2, 32), 256, 0, stream>>>((const ushort_t*)Vb, (ushort_t*)Vt);
    flash_attn<<<dim3(8, 32), 256, 0, stream>>>(
        (const ushort_t*)Qb, (const ushort_t*)Kb, (const ushort_t*)Vt, E4,
        0.08838834764831845f);

    // O-proj: hi-only, KSPLIT=2, grid 64x4x2 = 512; fused reduce2 + residual + LN
    gemm_w<EPI_PART, 1, 2><<<dim3(NR / 128, Dm / 128, 2), 256, 0, stream>>>(
        (const ushort_t*)E4, (const ushort_t*)Wohi, nullptr,
        nullptr, P3, nullptr, nullptr, nullptr, NR, Dm, K1);
    reduce2_ln_kernel<<<NR / 4, 256, 0, stream>>>(P3, (long)NR * Dm, x, ln_w, ln_b, out);
}

// Round 18
// 708.673 us; speedup vs baseline: 1.0405x; 1.0405x over previous
//
#include <hip/hip_runtime.h>
#include <cstdint>

typedef unsigned short ushort_t;
typedef _Float16 half_t;
typedef __attribute__((ext_vector_type(8))) short short8;
typedef __attribute__((ext_vector_type(8))) half_t half8;
typedef __attribute__((ext_vector_type(4))) float f32x4;

// ---------------- helpers ----------------
__device__ __forceinline__ void gld_lds16(const ushort_t* g, ushort_t* l) {
    __builtin_amdgcn_global_load_lds((const __attribute__((address_space(1))) void*)g,
                                     (__attribute__((address_space(3))) void*)l,
                                     16, 0, 0);
}

// spline/silu expansion of one scalar -> 9 plane values
__device__ __forceinline__ void expand9(float x, float* w9) {
    float si = x / (1.0f + __expf(-x));
    float u = (x + 2.2f) * 2.5f;
    int ji = (int)floorf(u);
    float f = u - (float)ji;
    if (!(ji >= 0 && ji <= 10)) ji = -100;      // outside knot range -> all bases 0
    float f2 = f * f, f3 = f2 * f;
    float w_i   = f3 * (1.0f / 6.0f);
    float w_im1 = (1.0f + 3.0f * f + 3.0f * f2 - 3.0f * f3) * (1.0f/6.0f);
    float w_im2 = (4.0f - 6.0f * f2 + 3.0f * f3) * (1.0f/6.0f);
    float omf = 1.0f - f;
    float w_im3 = omf * omf * omf * (1.0f / 6.0f);
    w9[0] = si;
    #pragma unroll
    for (int c = 0; c < 8; ++c) {
        float v = 0.0f;
        v = (c == ji    ) ? w_i   : v;
        v = (c == ji - 1) ? w_im1 : v;
        v = (c == ji - 2) ? w_im2 : v;
        v = (c == ji - 3) ? w_im3 : v;
        w9[c + 1] = v;
    }
}

// ---------------- expand: X fp32 [N][IN] -> E fp16 [N][9][IN] ----------------
template<int IN>
__global__ void expand_kernel(const float* __restrict__ X, half_t* __restrict__ E, int nrows) {
    int idx = blockIdx.x * 256 + threadIdx.x;
    if (idx >= nrows * IN) return;
    int n = idx / IN, i = idx % IN;
    float w9[9];
    expand9(X[idx], w9);
    half_t* Er = E + (long)n * 9 * IN + i;
    #pragma unroll
    for (int c = 0; c < 9; ++c) Er[(long)c * IN] = (half_t)w9[c];
}

// ---------------- fused weight pack: all six layers in one launch ----------------
// (correctness proven r17: absmax bit-identical). lo-planes only for k1/k2.
__global__ void pack_all(const float* __restrict__ k1b, const float* __restrict__ k1s,
                         const float* __restrict__ k2b, const float* __restrict__ k2s,
                         const float* __restrict__ qb,  const float* __restrict__ qs,
                         const float* __restrict__ kb,  const float* __restrict__ ks_,
                         const float* __restrict__ vb,  const float* __restrict__ vs,
                         const float* __restrict__ ob,  const float* __restrict__ os_,
                         half_t* __restrict__ W1hi, half_t* __restrict__ W1lo,
                         half_t* __restrict__ W2hi, half_t* __restrict__ W2lo,
                         half_t* __restrict__ Wqhi, half_t* __restrict__ Wohi) {
    int idx = blockIdx.x * 256 + threadIdx.x;   // 0 .. 2097152
    const float* base; const float* spline; half_t* Whi; half_t* Wlo; int IN; int li;
    if (idx < 524288)       { base = k1b; spline = k1s; Whi = W1hi; Wlo = W1lo; IN = 512;  li = idx; }
    else if (idx < 1048576) { base = k2b; spline = k2s; Whi = W2hi; Wlo = W2lo; IN = 1024; li = idx - 524288; }
    else if (idx < 1310720) { base = qb;  spline = qs;  Whi = Wqhi;                      Wlo = nullptr; IN = 512; li = idx - 1048576; }
    else if (idx < 1572864) { base = kb;  spline = ks_; Whi = Wqhi + (size_t)512 * 4608; Wlo = nullptr; IN = 512; li = idx - 1310720; }
    else if (idx < 1835008) { base = vb;  spline = vs;  Whi = Wqhi + (size_t)1024 * 4608; Wlo = nullptr; IN = 512; li = idx - 1572864; }
    else                    { base = ob;  spline = os_; Whi = Wohi; Wlo = nullptr; IN = 512; li = idx - 1835008; }
    int o = li / IN, i = li % IN;
    long r0 = (long)o * 9 * IN + i;
    long widx = (long)o * IN + i;
    float w[9];
    w[0] = base[widx];
    const f32x4* sp = (const f32x4*)(spline + widx * 8);
    f32x4 s0 = sp[0], s1 = sp[1];
    w[1] = s0[0]; w[2] = s0[1]; w[3] = s0[2]; w[4] = s0[3];
    w[5] = s1[0]; w[6] = s1[1]; w[7] = s1[2]; w[8] = s1[3];
    #pragma unroll
    for (int c = 0; c < 9; ++c) {
        half_t hi = (half_t)w[c];
        Whi[r0 + (long)c * IN] = hi;
        if (Wlo) Wlo[r0 + (long)c * IN] = (half_t)(w[c] - (float)hi);
    }
}

enum { EPI_PART = 0, EPI_QKV = 1, EPI_RELU = 4 };

// ---------------- weight GEMM: r6-proven 2-barrier structure (875 TF measured r13) ----------------
template<int EPI, int NPASS, int KSPLIT>
__global__ __launch_bounds__(256, 4)
void gemm_w(const ushort_t* __restrict__ A, const ushort_t* __restrict__ Bhi,
            const ushort_t* __restrict__ Blo, float* __restrict__ Cf, float* __restrict__ P,
            half_t* __restrict__ Qp, half_t* __restrict__ Kp, half_t* __restrict__ Vp,
            int M, int N, int K) {
    __shared__ __attribute__((aligned(16))) ushort_t As[128 * 64];
    __shared__ __attribute__((aligned(16))) ushort_t Bs[128 * 64];
    const int tid = threadIdx.x;
    const int lane = tid & 63;
    const int wave = tid >> 6;
    const int wm = wave >> 1, wn = wave & 1;
    const int bm = blockIdx.x * 128, bn = blockIdx.y * 128;
    const int l15 = lane & 15, l16 = lane >> 4;
    const int NT = K >> 6;
    const int TV = (NPASS == 2) ? 2 * NT : NT;
    int kc, t0;
    if constexpr (KSPLIT > 1) { kc = TV / KSPLIT; t0 = blockIdx.z * kc; }
    else { kc = TV; t0 = 0; }

    f32x4 acc[4][4];
    #pragma unroll
    for (int m = 0; m < 4; ++m)
        #pragma unroll
        for (int n = 0; n < 4; ++n) acc[m][n] = (f32x4){0.f, 0.f, 0.f, 0.f};

    for (int u = 0; u < kc; ++u) {
        int tt = t0 + u;
        int pass = (tt >= NT) ? 1 : 0;
        int kt = (tt - (pass ? NT : 0)) << 6;
        const ushort_t* Bb = pass ? Blo : Bhi;
        #pragma unroll
        for (int r = 0; r < 4; ++r) {
            int ch = r * 256 + tid;
            int row = ch >> 3, c = ch & 7;
            gld_lds16(A + (long)(bm + row) * K + kt + ((c ^ (row & 7)) << 3), &As[ch * 8]);
        }
        #pragma unroll
        for (int r = 0; r < 4; ++r) {
            int ch = r * 256 + tid;
            int row = ch >> 3, c = ch & 7;
            gld_lds16(Bb + (long)(bn + row) * K + kt + ((c ^ (row & 7)) << 3), &Bs[ch * 8]);
        }
        __syncthreads();
        #pragma unroll
        for (int kk = 0; kk < 2; ++kk) {
            half8 af[4], bfr[4];
            #pragma unroll
            for (int m = 0; m < 4; ++m) {
                int row = wm * 64 + m * 16 + l15;
                af[m] = __builtin_bit_cast(half8, *(const short8*)&As[row * 64 + (((kk * 4 + l16) ^ (row & 7)) << 3)]);
            }
            #pragma unroll
            for (int n = 0; n < 4; ++n) {
                int row = wn * 64 + n * 16 + l15;
                bfr[n] = __builtin_bit_cast(half8, *(const short8*)&Bs[row * 64 + (((kk * 4 + l16) ^ (row & 7)) << 3)]);
            }
            #pragma unroll
            for (int m = 0; m < 4; ++m)
                #pragma unroll
                for (int n = 0; n < 4; ++n)
                    acc[m][n] = __builtin_amdgcn_mfma_f32_16x16x32_f16(af[m], bfr[n], acc[m][n], 0, 0, 0);
        }
        __syncthreads();
    }

    // epilogue: C/D layout col=lane&15, row=(lane>>4)*4+j (m89-verified)
    #pragma unroll
    for (int m = 0; m < 4; ++m) {
        #pragma unroll
        for (int n = 0; n < 4; ++n) {
            #pragma unroll
            for (int j = 0; j < 4; ++j) {
                int row = bm + wm * 64 + m * 16 + l16 * 4 + j;
                int col = bn + wn * 64 + n * 16 + l15;
                float v = acc[m][n][j];
                if constexpr (KSPLIT > 1) {
                    P[(size_t)blockIdx.z * M * N + (long)row * N + col] = v;
                } else if constexpr (EPI == EPI_RELU) {
                    Cf[(long)row * N + col] = fmaxf(v, 0.0f);
                } else if constexpr (EPI == EPI_QKV) {
                    int which = col >> 9, w5 = col & 511, h = w5 >> 7, d = w5 & 127;
                    int b = row >> 10, ss = row & 1023;
                    half_t* dst = (which == 0) ? Qp : ((which == 1) ? Kp : Vp);
                    dst[(((long)(b * 4 + h) * 1024 + ss) << 7) + d] = (half_t)v;
                }
            }
        }
    }
}

// ---------------- fused flash attention (r16-proven): writes AO fp32 coalesced ----------------
__global__ __launch_bounds__(256, 1)
void flash_attn(const ushort_t* __restrict__ Q, const ushort_t* __restrict__ Kb,
                const ushort_t* __restrict__ Vt, float* __restrict__ AO, float scale) {
    constexpr int TS = 128 * 128;
    __shared__ __attribute__((aligned(16))) ushort_t Qs[TS];
    __shared__ __attribute__((aligned(16))) ushort_t Ks[TS];
    __shared__ __attribute__((aligned(16))) ushort_t Vs[TS];
    __shared__ __attribute__((aligned(16))) half_t  Ps[TS];
    const int tid = threadIdx.x;
    const int lane = tid & 63;
    const int w = tid >> 6;
    const int l15 = lane & 15, l16 = lane >> 4;
    const int bm = blockIdx.x * 128;
    const int bh = blockIdx.y;
    const ushort_t* Qg = Q + (long)bh * 1024 * 128;
    const ushort_t* Kg = Kb + (long)bh * 1024 * 128;
    const ushort_t* Vg = Vt + (long)bh * 128 * 1024;

    #pragma unroll
    for (int r = 0; r < 8; ++r) {
        int ch = r * 256 + tid;
        int row = ch >> 4, c = ch & 15;
        gld_lds16(Qg + (long)(bm + row) * 128 + ((c ^ (row & 15)) << 3), &Qs[ch * 8]);
    }
    __syncthreads();
    half8 qf[2][4];
    #pragma unroll
    for (int mf = 0; mf < 2; ++mf)
        #pragma unroll
        for (int kk = 0; kk < 4; ++kk) {
            int row = w * 32 + mf * 16 + l15;
            qf[mf][kk] = __builtin_bit_cast(half8, *(const short8*)&Qs[row * 128 + (((kk * 4 + l16) ^ (row & 15)) << 3)]);
        }

    f32x4 o_acc[2][8];
    #pragma unroll
    for (int mf = 0; mf < 2; ++mf)
        #pragma unroll
        for (int nf = 0; nf < 8; ++nf) o_acc[mf][nf] = (f32x4){0.f, 0.f, 0.f, 0.f};
    float m_run[2][4], l_run[2][4];
    #pragma unroll
    for (int mf = 0; mf < 2; ++mf)
        #pragma unroll
        for (int j = 0; j < 4; ++j) { m_run[mf][j] = -3.0e38f; l_run[mf][j] = 0.f; }

    for (int t = 0; t < 8; ++t) {
        int kv0 = t * 128;
        #pragma unroll
        for (int r = 0; r < 8; ++r) {
            int ch = r * 256 + tid;
            int row = ch >> 4, c = ch & 15;
            gld_lds16(Kg + (long)(kv0 + row) * 128 + ((c ^ (row & 15)) << 3), &Ks[ch * 8]);
        }
        #pragma unroll
        for (int r = 0; r < 8; ++r) {
            int ch = r * 256 + tid;
            int row = ch >> 4, c = ch & 15;
            gld_lds16(Vg + (long)row * 1024 + kv0 + ((c ^ (row & 15)) << 3), (ushort_t*)&Vs[ch * 8]);
        }
        __syncthreads();
        f32x4 s_acc[2][8];
        #pragma unroll
        for (int mf = 0; mf < 2; ++mf)
            #pragma unroll
            for (int nf = 0; nf < 8; ++nf) s_acc[mf][nf] = (f32x4){0.f, 0.f, 0.f, 0.f};
        #pragma unroll
        for (int nf = 0; nf < 8; ++nf) {
            #pragma unroll
            for (int kk = 0; kk < 4; ++kk) {
                int row = nf * 16 + l15;
                half8 bf = __builtin_bit_cast(half8, *(const short8*)&Ks[row * 128 + (((kk * 4 + l16) ^ (row & 15)) << 3)]);
                #pragma unroll
                for (int mf = 0; mf < 2; ++mf)
                    s_acc[mf][nf] = __builtin_amdgcn_mfma_f32_16x16x32_f16(qf[mf][kk], bf, s_acc[mf][nf], 0, 0, 0);
            }
        }
        #pragma unroll
        for (int mf = 0; mf < 2; ++mf) {
            #pragma unroll
            for (int j = 0; j < 4; ++j) {
                float rmax = -3.0e38f;
                #pragma unroll
                for (int nf = 0; nf < 8; ++nf) rmax = fmaxf(rmax, s_acc[mf][nf][j]);
                #pragma unroll
                for (int off = 1; off < 16; off <<= 1) rmax = fmaxf(rmax, __shfl_xor(rmax, off));
                float m_new = fmaxf(m_run[mf][j], rmax * scale);
                float alpha = __expf(m_run[mf][j] - m_new);
                m_run[mf][j] = m_new;
                float rsum = 0.f;
                #pragma unroll
                for (int nf = 0; nf < 8; ++nf) {
                    float pv = __expf(s_acc[mf][nf][j] * scale - m_new);
                    s_acc[mf][nf][j] = pv;
                    rsum += pv;
                }
                #pragma unroll
                for (int off = 1; off < 16; off <<= 1) rsum += __shfl_xor(rsum, off);
                l_run[mf][j] = l_run[mf][j] * alpha + rsum;
                #pragma unroll
                for (int nf = 0; nf < 8; ++nf) o_acc[mf][nf][j] *= alpha;
            }
        }
        #pragma unroll
        for (int mf = 0; mf < 2; ++mf)
            #pragma unroll
            for (int nf = 0; nf < 8; ++nf)
                #pragma unroll
                for (int j = 0; j < 4; ++j) {
                    int row = w * 32 + mf * 16 + l16 * 4 + j;
                    int col = nf * 16 + l15;
                    int sch = (col >> 3) ^ (row & 15);
                    Ps[row * 128 + (sch << 3) + (col & 7)] = (half_t)s_acc[mf][nf][j];
                }
        __syncthreads();
        half8 pf[2][4];
        #pragma unroll
        for (int mf = 0; mf < 2; ++mf)
            #pragma unroll
            for (int kk = 0; kk < 4; ++kk) {
                int row = w * 32 + mf * 16 + l15;
                pf[mf][kk] = __builtin_bit_cast(half8, *(const short8*)&Ps[row * 128 + (((kk * 4 + l16) ^ (row & 15)) << 3)]);
            }
        #pragma unroll
        for (int nf = 0; nf < 8; ++nf) {
            #pragma unroll
            for (int kk = 0; kk < 4; ++kk) {
                int row = nf * 16 + l15;
                half8 bf = __builtin_bit_cast(half8, *(const short8*)&Vs[row * 128 + (((kk * 4 + l16) ^ (row & 15)) << 3)]);
                #pragma unroll
                for (int mf = 0; mf < 2; ++mf)
                    o_acc[mf][nf] = __builtin_amdgcn_mfma_f32_16x16x32_f16(pf[mf][kk], bf, o_acc[mf][nf], 0, 0, 0);
            }
        }
        __syncthreads();
    }
    int b = bh >> 2, h = bh & 3;
    #pragma unroll
    for (int mf = 0; mf < 2; ++mf) {
        #pragma unroll
        for (int nf = 0; nf < 8; ++nf) {
            #pragma unroll
            for (int j = 0; j < 4; ++j) {
                int row = bm + w * 32 + mf * 16 + l16 * 4 + j;
                int col = nf * 16 + l15;
                AO[(long)(b * 1024 + row) * 512 + h * 128 + col] = o_acc[mf][nf][j] / l_run[mf][j];
            }
        }
    }
}

// ---------------- split-K reduction ----------------
template<int KS, bool RELU>
__global__ void reduce_kernel(const float* __restrict__ P, float* __restrict__ out, long MN) {
    long i = ((long)blockIdx.x * 256 + threadIdx.x) * 4;
    if (i >= MN) return;
    f32x4 s = *(const f32x4*)&P[i];
    #pragma unroll
    for (int zz = 1; zz < KS; ++zz) {
        f32x4 t = *(const f32x4*)&P[(size_t)zz * MN + i];
        s += t;
    }
    if constexpr (RELU) {
        s[0] = fmaxf(s[0], 0.f); s[1] = fmaxf(s[1], 0.f);
        s[2] = fmaxf(s[2], 0.f); s[3] = fmaxf(s[3], 0.f);
    }
    *(f32x4*)&out[i] = s;
}

// ---------------- V transpose ----------------
__global__ void transpose_v(const ushort_t* __restrict__ V, ushort_t* __restrict__ Vt) {
    __shared__ ushort_t t[64][72];
    int s0 = blockIdx.x * 64, d0 = blockIdx.y * 64, bh = blockIdx.z;
    const ushort_t* Vb = V + (long)bh * 1024 * 128;
    ushort_t* Vtb = Vt + (long)bh * 128 * 1024;
    int tid = threadIdx.x;
    int r = tid >> 2, g = tid & 3;
    #pragma unroll
    for (int j = 0; j < 16; ++j)
        t[r][g * 16 + j] = Vb[(long)(s0 + r) * 128 + d0 + g * 16 + j];
    __syncthreads();
    #pragma unroll
    for (int j = 0; j < 16; ++j)
        Vtb[(long)(d0 + r) * 1024 + s0 + g * 16 + j] = t[g * 16 + j][r];
}

// ---------------- fused split-K2 reduce + residual + LayerNorm (rows of 512) ----------------
__global__ void reduce2_ln_kernel(const float* __restrict__ P, long MN,
                                  const float* __restrict__ X,
                                  const float* __restrict__ g, const float* __restrict__ b,
                                  float* __restrict__ out) {
    long row = (long)blockIdx.x * 4 + (threadIdx.x >> 6);
    int lane = threadIdx.x & 63;
    long base = row * 512 + lane * 8;
    f32x4 p0 = *(const f32x4*)&P[base],      p1 = *(const f32x4*)&P[base + 4];
    f32x4 q0 = *(const f32x4*)&P[MN + base], q1 = *(const f32x4*)&P[MN + base + 4];
    f32x4 x0 = *(const f32x4*)&X[base],      x1 = *(const f32x4*)&X[base + 4];
    float y[8];
    #pragma unroll
    for (int j = 0; j < 4; ++j) {
        y[j]     = (p0[j] + q0[j]) + x0[j];
        y[j + 4] = (p1[j] + q1[j]) + x1[j];
    }
    float s = 0.f;
    #pragma unroll
    for (int j = 0; j < 8; ++j) s += y[j];
    #pragma unroll
    for (int off = 32; off > 0; off >>= 1) s += __shfl_xor(s, off);
    float mu = s * (1.0f / 512.0f);
    float vs = 0.f;
    #pragma unroll
    for (int j = 0; j < 8; ++j) { float d = y[j] - mu; vs += d * d; }
    #pragma unroll
    for (int off = 32; off > 0; off >>= 1) vs += __shfl_xor(vs, off);
    float r = rsqrtf(vs * (1.0f / 512.0f) + 1e-5f);
    f32x4 w0 = *(const f32x4*)&g[lane * 8], w1 = *(const f32x4*)&g[lane * 8 + 4];
    f32x4 b0 = *(const f32x4*)&b[lane * 8], b1 = *(const f32x4*)&b[lane * 8 + 4];
    f32x4 r0, r1;
    #pragma unroll
    for (int j = 0; j < 4; ++j) {
        r0[j] = (y[j] - mu) * r * w0[j] + b0[j];
        r1[j] = (y[j + 4] - mu) * r * w1[j] + b1[j];
    }
    *(f32x4*)&out[base] = r0;
    *(f32x4*)&out[base + 4] = r1;
}

// ---------------- launch ----------------
extern "C" void kernel_launch(void* const* d_in, const int* in_sizes, int n_in,
                              void* d_out, int out_size, void* d_ws, size_t ws_size,
                              hipStream_t stream) {
    const float* x         = (const float*)d_in[0];
    const float* k1_base   = (const float*)d_in[1];
    const float* k1_spline = (const float*)d_in[2];
    const float* k2_base   = (const float*)d_in[3];
    const float* k2_spline = (const float*)d_in[4];
    const float* q_base    = (const float*)d_in[5];
    const float* q_spline  = (const float*)d_in[6];
    const float* k_base    = (const float*)d_in[7];
    const float* k_spline  = (const float*)d_in[8];
    const float* v_base    = (const float*)d_in[9];
    const float* v_spline  = (const float*)d_in[10];
    const float* o_base    = (const float*)d_in[11];
    const float* o_spline  = (const float*)d_in[12];
    const float* ln_w      = (const float*)d_in[13];
    const float* ln_b      = (const float*)d_in[14];
    float* out = (float*)d_out;

    constexpr int Dm = 512, HD = 1024, NR = 8192;
    constexpr int K1 = 9 * Dm;   // 4608
    constexpr int K2 = 9 * HD;   // 9216
    constexpr size_t MB = 1024 * 1024;

    char* p = (char*)d_ws;
    size_t off = 0;
    auto take = [&](size_t bytes) -> char* {
        char* r = p + off;
        off += (bytes + 255) & ~(size_t)255;
        return r;
    };
    half_t* W1hi = (half_t*)take((size_t)HD * K1 * 2);        //  9 MB
    half_t* W2hi = (half_t*)take((size_t)Dm * K2 * 2);        //  9 MB
    half_t* Wqhi = (half_t*)take((size_t)3 * Dm * K1 * 2);    // 13.5 MB
    half_t* Wohi = (half_t*)take((size_t)Dm * K1 * 2);        //  4.5 MB
    half_t* W1lo = (half_t*)take((size_t)HD * K1 * 2);
    half_t* W2lo = (half_t*)take((size_t)Dm * K2 * 2);
    char*   A    = take((size_t)152 * MB);                    // total 206 MB (< 224 proven-safe)
    (void)ws_size; (void)in_sizes; (void)n_in; (void)out_size;

    // arena phase map (MB):
    // A: E1 @0..72 | H1 fp32 @72..104 (direct ReLU epilogue)
    // B: E2c @0..72 | H1 @72..104 | P2 @104..136 (4x8) | H2 @136..152
    // C: E3 @0..72 | Q @72..80 K @80..88 V @88..96 | H2 @136..152
    // D: Vt @96..104 (V dead) | flash: reads Q/K/Vt, writes AO fp32 @104..120
    // E: E4 @0..72 (E3 dead) | P3 @120..152 (2x16) | fused reduce2+LN reads P3
    half_t* E1   = (half_t*)(A);
    float*  H1   = (float*)(A + 72 * MB);
    half_t* E2   = (half_t*)(A);
    float*  P2   = (float*)(A + 104 * MB);
    float*  H2   = (float*)(A + 136 * MB);
    half_t* E3   = (half_t*)(A);
    half_t* Qb   = (half_t*)(A + 72 * MB);
    half_t* Kb   = (half_t*)(A + 80 * MB);
    half_t* Vb   = (half_t*)(A + 88 * MB);
    half_t* Vt   = (half_t*)(A + 96 * MB);
    float*  AO   = (float*)(A + 104 * MB);
    half_t* E4   = (half_t*)(A);
    float*  P3   = (float*)(A + 120 * MB);

    // single fused pack launch (proven r17); q/k/v/o layers are hi-only
    pack_all<<<2097152 / 256, 256, 0, stream>>>(
        k1_base, k1_spline, k2_base, k2_spline, q_base, q_spline,
        k_base, k_spline, v_base, v_spline, o_base, o_spline,
        W1hi, W1lo, W2hi, W2lo, Wqhi, Wohi);

    // KAN1: hi+lo serial, direct ReLU epilogue, grid 64x8 = 512
    expand_kernel<Dm><<<(NR * Dm) / 256, 256, 0, stream>>>(x, E1, NR);
    gemm_w<EPI_RELU, 2, 1><<<dim3(NR / 128, HD / 128, 1), 256, 0, stream>>>(
        (const ushort_t*)E1, (const ushort_t*)W1hi, (const ushort_t*)W1lo,
        H1, nullptr, nullptr, nullptr, nullptr, NR, HD, K1);

    // KAN2 (2 M-chunks, hi+lo, KSPLIT=4): grid 32x4x4 = 512
    for (int c = 0; c < 2; ++c) {
        expand_kernel<HD><<<(4096 * HD) / 256, 256, 0, stream>>>(H1 + (size_t)c * 4096 * HD, E2, 4096);
        gemm_w<EPI_PART, 2, 4><<<dim3(4096 / 128, Dm / 128, 4), 256, 0, stream>>>(
            (const ushort_t*)E2, (const ushort_t*)W2hi, (const ushort_t*)W2lo,
            nullptr, P2, nullptr, nullptr, nullptr, 4096, Dm, K2);
        reduce_kernel<4, false><<<(4096 * Dm) / 1024, 256, 0, stream>>>(P2, H2 + (size_t)c * 4096 * Dm, (long)4096 * Dm);
    }

    // QKV: hi-only single pass, direct scatter, grid 64x12 = 768 (3/CU)
    expand_kernel<Dm><<<(NR * Dm) / 256, 256, 0, stream>>>(H2, E3, NR);
    gemm_w<EPI_QKV, 1, 1><<<dim3(NR / 128, (3 * Dm) / 128, 1), 256, 0, stream>>>(
        (const ushort_t*)E3, (const ushort_t*)Wqhi, nullptr,
        nullptr, nullptr, Qb, Kb, Vb, NR, 3 * Dm, K1);

    // attention: Vt transpose; fused flash -> AO (coalesced), grid 8x32 = 256
    transpose_v<<<dim3(16, 2, 32), 256, 0, stream>>>((const ushort_t*)Vb, (ushort_t*)Vt);
    flash_attn<<<dim3(8, 32), 256, 0, stream>>>(
        (const ushort_t*)Qb, (const ushort_t*)Kb, (const ushort_t*)Vt, AO,
        0.08838834764831845f);

    // O-proj: E4 = expand(AO); hi-only, KSPLIT=2, grid 64x4x2 = 512; fused reduce2+res+LN
    expand_kernel<Dm><<<(NR * Dm) / 256, 256, 0, stream>>>(AO, E4, NR);
    gemm_w<EPI_PART, 1, 2><<<dim3(NR / 128, Dm / 128, 2), 256, 0, stream>>>(
        (const ushort_t*)E4, (const ushort_t*)Wohi, nullptr,
        nullptr, P3, nullptr, nullptr, nullptr, NR, Dm, K1);
    reduce2_ln_kernel<<<NR / 4, 256, 0, stream>>>(P3, (long)NR * Dm, x, ln_w, ln_b, out);
}

// Round 19
// 627.956 us; speedup vs baseline: 1.1743x; 1.1285x over previous
//
#include <hip/hip_runtime.h>
#include <cstdint>

typedef unsigned short ushort_t;
typedef _Float16 half_t;
typedef __attribute__((ext_vector_type(8))) short short8;
typedef __attribute__((ext_vector_type(8))) half_t half8;
typedef __attribute__((ext_vector_type(4))) float f32x4;

// ---------------- helpers ----------------
__device__ __forceinline__ void gld_lds16(const ushort_t* g, ushort_t* l) {
    __builtin_amdgcn_global_load_lds((const __attribute__((address_space(1))) void*)g,
                                     (__attribute__((address_space(3))) void*)l,
                                     16, 0, 0);
}

// spline/silu expansion of one scalar -> 9 plane values
__device__ __forceinline__ void expand9(float x, float* w9) {
    float si = x / (1.0f + __expf(-x));
    float u = (x + 2.2f) * 2.5f;
    int ji = (int)floorf(u);
    float f = u - (float)ji;
    if (!(ji >= 0 && ji <= 10)) ji = -100;      // outside knot range -> all bases 0
    float f2 = f * f, f3 = f2 * f;
    float w_i   = f3 * (1.0f / 6.0f);
    float w_im1 = (1.0f + 3.0f * f + 3.0f * f2 - 3.0f * f3) * (1.0f/6.0f);
    float w_im2 = (4.0f - 6.0f * f2 + 3.0f * f3) * (1.0f/6.0f);
    float omf = 1.0f - f;
    float w_im3 = omf * omf * omf * (1.0f / 6.0f);
    w9[0] = si;
    #pragma unroll
    for (int c = 0; c < 8; ++c) {
        float v = 0.0f;
        v = (c == ji    ) ? w_i   : v;
        v = (c == ji - 1) ? w_im1 : v;
        v = (c == ji - 2) ? w_im2 : v;
        v = (c == ji - 3) ? w_im3 : v;
        w9[c + 1] = v;
    }
}

// ---------------- expand: X fp32 [N][IN] -> E fp16 [N][9][IN] ----------------
template<int IN>
__global__ void expand_kernel(const float* __restrict__ X, half_t* __restrict__ E, int nrows) {
    int idx = blockIdx.x * 256 + threadIdx.x;
    if (idx >= nrows * IN) return;
    int n = idx / IN, i = idx % IN;
    float w9[9];
    expand9(X[idx], w9);
    half_t* Er = E + (long)n * 9 * IN + i;
    #pragma unroll
    for (int c = 0; c < 9; ++c) Er[(long)c * IN] = (half_t)w9[c];
}

// ---------------- fused weight pack: all six layers in one launch (r17-proven) ----------------
__global__ void pack_all(const float* __restrict__ k1b, const float* __restrict__ k1s,
                         const float* __restrict__ k2b, const float* __restrict__ k2s,
                         const float* __restrict__ qb,  const float* __restrict__ qs,
                         const float* __restrict__ kb,  const float* __restrict__ ks_,
                         const float* __restrict__ vb,  const float* __restrict__ vs,
                         const float* __restrict__ ob,  const float* __restrict__ os_,
                         half_t* __restrict__ W1hi, half_t* __restrict__ W1lo,
                         half_t* __restrict__ W2hi, half_t* __restrict__ W2lo,
                         half_t* __restrict__ Wqhi, half_t* __restrict__ Wohi) {
    int idx = blockIdx.x * 256 + threadIdx.x;   // 0 .. 2097152
    const float* base; const float* spline; half_t* Whi; half_t* Wlo; int IN; int li;
    if (idx < 524288)       { base = k1b; spline = k1s; Whi = W1hi; Wlo = W1lo; IN = 512;  li = idx; }
    else if (idx < 1048576) { base = k2b; spline = k2s; Whi = W2hi; Wlo = W2lo; IN = 1024; li = idx - 524288; }
    else if (idx < 1310720) { base = qb;  spline = qs;  Whi = Wqhi;                      Wlo = nullptr; IN = 512; li = idx - 1048576; }
    else if (idx < 1572864) { base = kb;  spline = ks_; Whi = Wqhi + (size_t)512 * 4608; Wlo = nullptr; IN = 512; li = idx - 1310720; }
    else if (idx < 1835008) { base = vb;  spline = vs;  Whi = Wqhi + (size_t)1024 * 4608; Wlo = nullptr; IN = 512; li = idx - 1572864; }
    else                    { base = ob;  spline = os_; Whi = Wohi; Wlo = nullptr; IN = 512; li = idx - 1835008; }
    int o = li / IN, i = li % IN;
    long r0 = (long)o * 9 * IN + i;
    long widx = (long)o * IN + i;
    float w[9];
    w[0] = base[widx];
    const f32x4* sp = (const f32x4*)(spline + widx * 8);
    f32x4 s0 = sp[0], s1 = sp[1];
    w[1] = s0[0]; w[2] = s0[1]; w[3] = s0[2]; w[4] = s0[3];
    w[5] = s1[0]; w[6] = s1[1]; w[7] = s1[2]; w[8] = s1[3];
    #pragma unroll
    for (int c = 0; c < 9; ++c) {
        half_t hi = (half_t)w[c];
        Whi[r0 + (long)c * IN] = hi;
        if (Wlo) Wlo[r0 + (long)c * IN] = (half_t)(w[c] - (float)hi);
    }
}

enum { EPI_PART = 0, EPI_QKV = 1, EPI_RELU = 4 };

// ---------------- weight GEMM: 2-barrier structure, hi/lo fused per K-tile ----------------
// 128x128 tile, 4 waves (2x2), BK=64. NPASS==2: stage A + Bhi + Blo per tile (48 KB LDS),
// 32 MFMA per barrier-pair, A staged ONCE (halves A traffic + halves barrier drains/MFMA).
// Swizzle chunk^(row&7) on both global source and ds_read (conflict-free, r7/r13-verified).
// KSPLIT>1 slices REAL K-tiles across blockIdx.z (each slice does hi+lo) -> fp32 P[z].
template<int EPI, int NPASS, int KSPLIT>
__global__ __launch_bounds__(256, 4)
void gemm_w(const ushort_t* __restrict__ A, const ushort_t* __restrict__ Bhi,
            const ushort_t* __restrict__ Blo, float* __restrict__ Cf, float* __restrict__ P,
            half_t* __restrict__ Qp, half_t* __restrict__ Kp, half_t* __restrict__ Vp,
            int M, int N, int K) {
    __shared__ __attribute__((aligned(16))) ushort_t As[128 * 64];
    __shared__ __attribute__((aligned(16))) ushort_t Bs[NPASS][128 * 64];
    const int tid = threadIdx.x;
    const int lane = tid & 63;
    const int wave = tid >> 6;
    const int wm = wave >> 1, wn = wave & 1;
    const int bm = blockIdx.x * 128, bn = blockIdx.y * 128;
    const int l15 = lane & 15, l16 = lane >> 4;
    const int NT = K >> 6;
    int kc, t0;
    if constexpr (KSPLIT > 1) { kc = NT / KSPLIT; t0 = blockIdx.z * kc; }
    else { kc = NT; t0 = 0; }

    f32x4 acc[4][4];
    #pragma unroll
    for (int m = 0; m < 4; ++m)
        #pragma unroll
        for (int n = 0; n < 4; ++n) acc[m][n] = (f32x4){0.f, 0.f, 0.f, 0.f};

    for (int u = 0; u < kc; ++u) {
        int kt = (t0 + u) << 6;
        #pragma unroll
        for (int r = 0; r < 4; ++r) {
            int ch = r * 256 + tid;             // A: 1024 chunks of 8 halves per 128x64 tile
            int row = ch >> 3, c = ch & 7;
            gld_lds16(A + (long)(bm + row) * K + kt + ((c ^ (row & 7)) << 3), &As[ch * 8]);
        }
        #pragma unroll
        for (int pp = 0; pp < NPASS; ++pp) {
            const ushort_t* Bb = pp ? Blo : Bhi;
            #pragma unroll
            for (int r = 0; r < 4; ++r) {
                int ch = r * 256 + tid;
                int row = ch >> 3, c = ch & 7;
                gld_lds16(Bb + (long)(bn + row) * K + kt + ((c ^ (row & 7)) << 3), &Bs[pp][ch * 8]);
            }
        }
        __syncthreads();
        #pragma unroll
        for (int pp = 0; pp < NPASS; ++pp) {
            #pragma unroll
            for (int kk = 0; kk < 2; ++kk) {
                half8 af[4], bfr[4];
                #pragma unroll
                for (int m = 0; m < 4; ++m) {
                    int row = wm * 64 + m * 16 + l15;
                    af[m] = __builtin_bit_cast(half8, *(const short8*)&As[row * 64 + (((kk * 4 + l16) ^ (row & 7)) << 3)]);
                }
                #pragma unroll
                for (int n = 0; n < 4; ++n) {
                    int row = wn * 64 + n * 16 + l15;
                    bfr[n] = __builtin_bit_cast(half8, *(const short8*)&Bs[pp][row * 64 + (((kk * 4 + l16) ^ (row & 7)) << 3)]);
                }
                #pragma unroll
                for (int m = 0; m < 4; ++m)
                    #pragma unroll
                    for (int n = 0; n < 4; ++n)
                        acc[m][n] = __builtin_amdgcn_mfma_f32_16x16x32_f16(af[m], bfr[n], acc[m][n], 0, 0, 0);
            }
        }
        __syncthreads();
    }

    // epilogue: C/D layout col=lane&15, row=(lane>>4)*4+j (m89-verified)
    #pragma unroll
    for (int m = 0; m < 4; ++m) {
        #pragma unroll
        for (int n = 0; n < 4; ++n) {
            #pragma unroll
            for (int j = 0; j < 4; ++j) {
                int row = bm + wm * 64 + m * 16 + l16 * 4 + j;
                int col = bn + wn * 64 + n * 16 + l15;
                float v = acc[m][n][j];
                if constexpr (KSPLIT > 1) {
                    P[(size_t)blockIdx.z * M * N + (long)row * N + col] = v;
                } else if constexpr (EPI == EPI_RELU) {
                    Cf[(long)row * N + col] = fmaxf(v, 0.0f);
                } else if constexpr (EPI == EPI_QKV) {
                    int which = col >> 9, w5 = col & 511, h = w5 >> 7, d = w5 & 127;
                    int b = row >> 10, ss = row & 1023;
                    half_t* dst = (which == 0) ? Qp : ((which == 1) ? Kp : Vp);
                    dst[(((long)(b * 4 + h) * 1024 + ss) << 7) + d] = (half_t)v;
                }
            }
        }
    }
}

// ---------------- fused flash attention (r16-proven): writes AO fp32 coalesced ----------------
__global__ __launch_bounds__(256, 1)
void flash_attn(const ushort_t* __restrict__ Q, const ushort_t* __restrict__ Kb,
                const ushort_t* __restrict__ Vt, float* __restrict__ AO, float scale) {
    constexpr int TS = 128 * 128;
    __shared__ __attribute__((aligned(16))) ushort_t Qs[TS];
    __shared__ __attribute__((aligned(16))) ushort_t Ks[TS];
    __shared__ __attribute__((aligned(16))) ushort_t Vs[TS];
    __shared__ __attribute__((aligned(16))) half_t  Ps[TS];
    const int tid = threadIdx.x;
    const int lane = tid & 63;
    const int w = tid >> 6;
    const int l15 = lane & 15, l16 = lane >> 4;
    const int bm = blockIdx.x * 128;
    const int bh = blockIdx.y;
    const ushort_t* Qg = Q + (long)bh * 1024 * 128;
    const ushort_t* Kg = Kb + (long)bh * 1024 * 128;
    const ushort_t* Vg = Vt + (long)bh * 128 * 1024;

    #pragma unroll
    for (int r = 0; r < 8; ++r) {
        int ch = r * 256 + tid;
        int row = ch >> 4, c = ch & 15;
        gld_lds16(Qg + (long)(bm + row) * 128 + ((c ^ (row & 15)) << 3), &Qs[ch * 8]);
    }
    __syncthreads();
    half8 qf[2][4];
    #pragma unroll
    for (int mf = 0; mf < 2; ++mf)
        #pragma unroll
        for (int kk = 0; kk < 4; ++kk) {
            int row = w * 32 + mf * 16 + l15;
            qf[mf][kk] = __builtin_bit_cast(half8, *(const short8*)&Qs[row * 128 + (((kk * 4 + l16) ^ (row & 15)) << 3)]);
        }

    f32x4 o_acc[2][8];
    #pragma unroll
    for (int mf = 0; mf < 2; ++mf)
        #pragma unroll
        for (int nf = 0; nf < 8; ++nf) o_acc[mf][nf] = (f32x4){0.f, 0.f, 0.f, 0.f};
    float m_run[2][4], l_run[2][4];
    #pragma unroll
    for (int mf = 0; mf < 2; ++mf)
        #pragma unroll
        for (int j = 0; j < 4; ++j) { m_run[mf][j] = -3.0e38f; l_run[mf][j] = 0.f; }

    for (int t = 0; t < 8; ++t) {
        int kv0 = t * 128;
        #pragma unroll
        for (int r = 0; r < 8; ++r) {
            int ch = r * 256 + tid;
            int row = ch >> 4, c = ch & 15;
            gld_lds16(Kg + (long)(kv0 + row) * 128 + ((c ^ (row & 15)) << 3), &Ks[ch * 8]);
        }
        #pragma unroll
        for (int r = 0; r < 8; ++r) {
            int ch = r * 256 + tid;
            int row = ch >> 4, c = ch & 15;
            gld_lds16(Vg + (long)row * 1024 + kv0 + ((c ^ (row & 15)) << 3), (ushort_t*)&Vs[ch * 8]);
        }
        __syncthreads();
        f32x4 s_acc[2][8];
        #pragma unroll
        for (int mf = 0; mf < 2; ++mf)
            #pragma unroll
            for (int nf = 0; nf < 8; ++nf) s_acc[mf][nf] = (f32x4){0.f, 0.f, 0.f, 0.f};
        #pragma unroll
        for (int nf = 0; nf < 8; ++nf) {
            #pragma unroll
            for (int kk = 0; kk < 4; ++kk) {
                int row = nf * 16 + l15;
                half8 bf = __builtin_bit_cast(half8, *(const short8*)&Ks[row * 128 + (((kk * 4 + l16) ^ (row & 15)) << 3)]);
                #pragma unroll
                for (int mf = 0; mf < 2; ++mf)
                    s_acc[mf][nf] = __builtin_amdgcn_mfma_f32_16x16x32_f16(qf[mf][kk], bf, s_acc[mf][nf], 0, 0, 0);
            }
        }
        #pragma unroll
        for (int mf = 0; mf < 2; ++mf) {
            #pragma unroll
            for (int j = 0; j < 4; ++j) {
                float rmax = -3.0e38f;
                #pragma unroll
                for (int nf = 0; nf < 8; ++nf) rmax = fmaxf(rmax, s_acc[mf][nf][j]);
                #pragma unroll
                for (int off = 1; off < 16; off <<= 1) rmax = fmaxf(rmax, __shfl_xor(rmax, off));
                float m_new = fmaxf(m_run[mf][j], rmax * scale);
                float alpha = __expf(m_run[mf][j] - m_new);
                m_run[mf][j] = m_new;
                float rsum = 0.f;
                #pragma unroll
                for (int nf = 0; nf < 8; ++nf) {
                    float pv = __expf(s_acc[mf][nf][j] * scale - m_new);
                    s_acc[mf][nf][j] = pv;
                    rsum += pv;
                }
                #pragma unroll
                for (int off = 1; off < 16; off <<= 1) rsum += __shfl_xor(rsum, off);
                l_run[mf][j] = l_run[mf][j] * alpha + rsum;
                #pragma unroll
                for (int nf = 0; nf < 8; ++nf) o_acc[mf][nf][j] *= alpha;
            }
        }
        #pragma unroll
        for (int mf = 0; mf < 2; ++mf)
            #pragma unroll
            for (int nf = 0; nf < 8; ++nf)
                #pragma unroll
                for (int j = 0; j < 4; ++j) {
                    int row = w * 32 + mf * 16 + l16 * 4 + j;
                    int col = nf * 16 + l15;
                    int sch = (col >> 3) ^ (row & 15);
                    Ps[row * 128 + (sch << 3) + (col & 7)] = (half_t)s_acc[mf][nf][j];
                }
        __syncthreads();
        half8 pf[2][4];
        #pragma unroll
        for (int mf = 0; mf < 2; ++mf)
            #pragma unroll
            for (int kk = 0; kk < 4; ++kk) {
                int row = w * 32 + mf * 16 + l15;
                pf[mf][kk] = __builtin_bit_cast(half8, *(const short8*)&Ps[row * 128 + (((kk * 4 + l16) ^ (row & 15)) << 3)]);
            }
        #pragma unroll
        for (int nf = 0; nf < 8; ++nf) {
            #pragma unroll
            for (int kk = 0; kk < 4; ++kk) {
                int row = nf * 16 + l15;
                half8 bf = __builtin_bit_cast(half8, *(const short8*)&Vs[row * 128 + (((kk * 4 + l16) ^ (row & 15)) << 3)]);
                #pragma unroll
                for (int mf = 0; mf < 2; ++mf)
                    o_acc[mf][nf] = __builtin_amdgcn_mfma_f32_16x16x32_f16(pf[mf][kk], bf, o_acc[mf][nf], 0, 0, 0);
            }
        }
        __syncthreads();
    }
    int b = bh >> 2, h = bh & 3;
    #pragma unroll
    for (int mf = 0; mf < 2; ++mf) {
        #pragma unroll
        for (int nf = 0; nf < 8; ++nf) {
            #pragma unroll
            for (int j = 0; j < 4; ++j) {
                int row = bm + w * 32 + mf * 16 + l16 * 4 + j;
                int col = nf * 16 + l15;
                AO[(long)(b * 1024 + row) * 512 + h * 128 + col] = o_acc[mf][nf][j] / l_run[mf][j];
            }
        }
    }
}

// ---------------- split-K reduction ----------------
template<int KS, bool RELU>
__global__ void reduce_kernel(const float* __restrict__ P, float* __restrict__ out, long MN) {
    long i = ((long)blockIdx.x * 256 + threadIdx.x) * 4;
    if (i >= MN) return;
    f32x4 s = *(const f32x4*)&P[i];
    #pragma unroll
    for (int zz = 1; zz < KS; ++zz) {
        f32x4 t = *(const f32x4*)&P[(size_t)zz * MN + i];
        s += t;
    }
    if constexpr (RELU) {
        s[0] = fmaxf(s[0], 0.f); s[1] = fmaxf(s[1], 0.f);
        s[2] = fmaxf(s[2], 0.f); s[3] = fmaxf(s[3], 0.f);
    }
    *(f32x4*)&out[i] = s;
}

// ---------------- V transpose ----------------
__global__ void transpose_v(const ushort_t* __restrict__ V, ushort_t* __restrict__ Vt) {
    __shared__ ushort_t t[64][72];
    int s0 = blockIdx.x * 64, d0 = blockIdx.y * 64, bh = blockIdx.z;
    const ushort_t* Vb = V + (long)bh * 1024 * 128;
    ushort_t* Vtb = Vt + (long)bh * 128 * 1024;
    int tid = threadIdx.x;
    int r = tid >> 2, g = tid & 3;
    #pragma unroll
    for (int j = 0; j < 16; ++j)
        t[r][g * 16 + j] = Vb[(long)(s0 + r) * 128 + d0 + g * 16 + j];
    __syncthreads();
    #pragma unroll
    for (int j = 0; j < 16; ++j)
        Vtb[(long)(d0 + r) * 1024 + s0 + g * 16 + j] = t[g * 16 + j][r];
}

// ---------------- fused split-K2 reduce + residual + LayerNorm (rows of 512) ----------------
__global__ void reduce2_ln_kernel(const float* __restrict__ P, long MN,
                                  const float* __restrict__ X,
                                  const float* __restrict__ g, const float* __restrict__ b,
                                  float* __restrict__ out) {
    long row = (long)blockIdx.x * 4 + (threadIdx.x >> 6);
    int lane = threadIdx.x & 63;
    long base = row * 512 + lane * 8;
    f32x4 p0 = *(const f32x4*)&P[base],      p1 = *(const f32x4*)&P[base + 4];
    f32x4 q0 = *(const f32x4*)&P[MN + base], q1 = *(const f32x4*)&P[MN + base + 4];
    f32x4 x0 = *(const f32x4*)&X[base],      x1 = *(const f32x4*)&X[base + 4];
    float y[8];
    #pragma unroll
    for (int j = 0; j < 4; ++j) {
        y[j]     = (p0[j] + q0[j]) + x0[j];
        y[j + 4] = (p1[j] + q1[j]) + x1[j];
    }
    float s = 0.f;
    #pragma unroll
    for (int j = 0; j < 8; ++j) s += y[j];
    #pragma unroll
    for (int off = 32; off > 0; off >>= 1) s += __shfl_xor(s, off);
    float mu = s * (1.0f / 512.0f);
    float vs = 0.f;
    #pragma unroll
    for (int j = 0; j < 8; ++j) { float d = y[j] - mu; vs += d * d; }
    #pragma unroll
    for (int off = 32; off > 0; off >>= 1) vs += __shfl_xor(vs, off);
    float r = rsqrtf(vs * (1.0f / 512.0f) + 1e-5f);
    f32x4 w0 = *(const f32x4*)&g[lane * 8], w1 = *(const f32x4*)&g[lane * 8 + 4];
    f32x4 b0 = *(const f32x4*)&b[lane * 8], b1 = *(const f32x4*)&b[lane * 8 + 4];
    f32x4 r0, r1;
    #pragma unroll
    for (int j = 0; j < 4; ++j) {
        r0[j] = (y[j] - mu) * r * w0[j] + b0[j];
        r1[j] = (y[j + 4] - mu) * r * w1[j] + b1[j];
    }
    *(f32x4*)&out[base] = r0;
    *(f32x4*)&out[base + 4] = r1;
}

// ---------------- launch ----------------
extern "C" void kernel_launch(void* const* d_in, const int* in_sizes, int n_in,
                              void* d_out, int out_size, void* d_ws, size_t ws_size,
                              hipStream_t stream) {
    const float* x         = (const float*)d_in[0];
    const float* k1_base   = (const float*)d_in[1];
    const float* k1_spline = (const float*)d_in[2];
    const float* k2_base   = (const float*)d_in[3];
    const float* k2_spline = (const float*)d_in[4];
    const float* q_base    = (const float*)d_in[5];
    const float* q_spline  = (const float*)d_in[6];
    const float* k_base    = (const float*)d_in[7];
    const float* k_spline  = (const float*)d_in[8];
    const float* v_base    = (const float*)d_in[9];
    const float* v_spline  = (const float*)d_in[10];
    const float* o_base    = (const float*)d_in[11];
    const float* o_spline  = (const float*)d_in[12];
    const float* ln_w      = (const float*)d_in[13];
    const float* ln_b      = (const float*)d_in[14];
    float* out = (float*)d_out;

    constexpr int Dm = 512, HD = 1024, NR = 8192;
    constexpr int K1 = 9 * Dm;   // 4608
    constexpr int K2 = 9 * HD;   // 9216
    constexpr size_t MB = 1024 * 1024;

    char* p = (char*)d_ws;
    size_t off = 0;
    auto take = [&](size_t bytes) -> char* {
        char* r = p + off;
        off += (bytes + 255) & ~(size_t)255;
        return r;
    };
    half_t* W1hi = (half_t*)take((size_t)HD * K1 * 2);        //  9 MB
    half_t* W2hi = (half_t*)take((size_t)Dm * K2 * 2);        //  9 MB
    half_t* Wqhi = (half_t*)take((size_t)3 * Dm * K1 * 2);    // 13.5 MB
    half_t* Wohi = (half_t*)take((size_t)Dm * K1 * 2);        //  4.5 MB
    half_t* W1lo = (half_t*)take((size_t)HD * K1 * 2);
    half_t* W2lo = (half_t*)take((size_t)Dm * K2 * 2);
    char*   A    = take((size_t)152 * MB);                    // total 206 MB (< 224 proven-safe)
    (void)ws_size; (void)in_sizes; (void)n_in; (void)out_size;

    // arena phase map (MB):
    // A: E1 @0..72 | H1 fp32 @72..104 (direct ReLU epilogue)
    // B: E2c @0..72 | H1 @72..104 | P2 @104..136 (4x8) | H2 @136..152
    // C: E3 @0..72 | Q @72..80 K @80..88 V @88..96 | H2 @136..152
    // D: Vt @96..104 (V dead) | flash: reads Q/K/Vt, writes AO fp32 @104..120
    // E: E4 @0..72 (E3 dead) | P3 @120..152 (2x16) | fused reduce2+LN reads P3
    half_t* E1   = (half_t*)(A);
    float*  H1   = (float*)(A + 72 * MB);
    half_t* E2   = (half_t*)(A);
    float*  P2   = (float*)(A + 104 * MB);
    float*  H2   = (float*)(A + 136 * MB);
    half_t* E3   = (half_t*)(A);
    half_t* Qb   = (half_t*)(A + 72 * MB);
    half_t* Kb   = (half_t*)(A + 80 * MB);
    half_t* Vb   = (half_t*)(A + 88 * MB);
    half_t* Vt   = (half_t*)(A + 96 * MB);
    float*  AO   = (float*)(A + 104 * MB);
    half_t* E4   = (half_t*)(A);
    float*  P3   = (float*)(A + 120 * MB);

    // single fused pack launch; q/k/v/o layers are hi-only
    pack_all<<<2097152 / 256, 256, 0, stream>>>(
        k1_base, k1_spline, k2_base, k2_spline, q_base, q_spline,
        k_base, k_spline, v_base, v_spline, o_base, o_spline,
        W1hi, W1lo, W2hi, W2lo, Wqhi, Wohi);

    // KAN1: hi+lo fused per K-tile (A staged once), direct ReLU epilogue, grid 64x8 = 512
    expand_kernel<Dm><<<(NR * Dm) / 256, 256, 0, stream>>>(x, E1, NR);
    gemm_w<EPI_RELU, 2, 1><<<dim3(NR / 128, HD / 128, 1), 256, 0, stream>>>(
        (const ushort_t*)E1, (const ushort_t*)W1hi, (const ushort_t*)W1lo,
        H1, nullptr, nullptr, nullptr, nullptr, NR, HD, K1);

    // KAN2 (2 M-chunks, hi+lo fused, KSPLIT=4 over real tiles): grid 32x4x4 = 512
    for (int c = 0; c < 2; ++c) {
        expand_kernel<HD><<<(4096 * HD) / 256, 256, 0, stream>>>(H1 + (size_t)c * 4096 * HD, E2, 4096);
        gemm_w<EPI_PART, 2, 4><<<dim3(4096 / 128, Dm / 128, 4), 256, 0, stream>>>(
            (const ushort_t*)E2, (const ushort_t*)W2hi, (const ushort_t*)W2lo,
            nullptr, P2, nullptr, nullptr, nullptr, 4096, Dm, K2);
        reduce_kernel<4, false><<<(4096 * Dm) / 1024, 256, 0, stream>>>(P2, H2 + (size_t)c * 4096 * Dm, (long)4096 * Dm);
    }

    // QKV: hi-only single pass, direct scatter, grid 64x12 = 768 (3/CU)
    expand_kernel<Dm><<<(NR * Dm) / 256, 256, 0, stream>>>(H2, E3, NR);
    gemm_w<EPI_QKV, 1, 1><<<dim3(NR / 128, (3 * Dm) / 128, 1), 256, 0, stream>>>(
        (const ushort_t*)E3, (const ushort_t*)Wqhi, nullptr,
        nullptr, nullptr, Qb, Kb, Vb, NR, 3 * Dm, K1);

    // attention: Vt transpose; fused flash -> AO (coalesced), grid 8x32 = 256
    transpose_v<<<dim3(16, 2, 32), 256, 0, stream>>>((const ushort_t*)Vb, (ushort_t*)Vt);
    flash_attn<<<dim3(8, 32), 256, 0, stream>>>(
        (const ushort_t*)Qb, (const ushort_t*)Kb, (const ushort_t*)Vt, AO,
        0.08838834764831845f);

    // O-proj: E4 = expand(AO); hi-only, KSPLIT=2, grid 64x4x2 = 512; fused reduce2+res+LN
    expand_kernel<Dm><<<(NR * Dm) / 256, 256, 0, stream>>>(AO, E4, NR);
    gemm_w<EPI_PART, 1, 2><<<dim3(NR / 128, Dm / 128, 2), 256, 0, stream>>>(
        (const ushort_t*)E4, (const ushort_t*)Wohi, nullptr,
        nullptr, P3, nullptr, nullptr, nullptr, NR, Dm, K1);
    reduce2_ln_kernel<<<NR / 4, 256, 0, stream>>>(P3, (long)NR * Dm, x, ln_w, ln_b, out);
}

// Round 20
// 625.802 us; speedup vs baseline: 1.1783x; 1.0034x over previous
//
#include <hip/hip_runtime.h>
#include <cstdint>

typedef unsigned short ushort_t;
typedef _Float16 half_t;
typedef __attribute__((ext_vector_type(8))) short short8;
typedef __attribute__((ext_vector_type(8))) half_t half8;
typedef __attribute__((ext_vector_type(4))) float f32x4;

// ---------------- helpers ----------------
__device__ __forceinline__ void gld_lds16(const ushort_t* g, ushort_t* l) {
    __builtin_amdgcn_global_load_lds((const __attribute__((address_space(1))) void*)g,
                                     (__attribute__((address_space(3))) void*)l,
                                     16, 0, 0);
}

// spline/silu expansion of one scalar -> 9 plane values
__device__ __forceinline__ void expand9(float x, float* w9) {
    float si = x / (1.0f + __expf(-x));
    float u = (x + 2.2f) * 2.5f;
    int ji = (int)floorf(u);
    float f = u - (float)ji;
    if (!(ji >= 0 && ji <= 10)) ji = -100;      // outside knot range -> all bases 0
    float f2 = f * f, f3 = f2 * f;
    float w_i   = f3 * (1.0f / 6.0f);
    float w_im1 = (1.0f + 3.0f * f + 3.0f * f2 - 3.0f * f3) * (1.0f/6.0f);
    float w_im2 = (4.0f - 6.0f * f2 + 3.0f * f3) * (1.0f/6.0f);
    float omf = 1.0f - f;
    float w_im3 = omf * omf * omf * (1.0f / 6.0f);
    w9[0] = si;
    #pragma unroll
    for (int c = 0; c < 8; ++c) {
        float v = 0.0f;
        v = (c == ji    ) ? w_i   : v;
        v = (c == ji - 1) ? w_im1 : v;
        v = (c == ji - 2) ? w_im2 : v;
        v = (c == ji - 3) ? w_im3 : v;
        w9[c + 1] = v;
    }
}

// ---------------- expand: X fp32 [N][IN] -> E fp16 [N][9][IN] ----------------
template<int IN>
__global__ void expand_kernel(const float* __restrict__ X, half_t* __restrict__ E, int nrows) {
    int idx = blockIdx.x * 256 + threadIdx.x;
    if (idx >= nrows * IN) return;
    int n = idx / IN, i = idx % IN;
    float w9[9];
    expand9(X[idx], w9);
    half_t* Er = E + (long)n * 9 * IN + i;
    #pragma unroll
    for (int c = 0; c < 9; ++c) Er[(long)c * IN] = (half_t)w9[c];
}

// ---------------- fused weight pack: all six layers in one launch (r17-proven) ----------------
__global__ void pack_all(const float* __restrict__ k1b, const float* __restrict__ k1s,
                         const float* __restrict__ k2b, const float* __restrict__ k2s,
                         const float* __restrict__ qb,  const float* __restrict__ qs,
                         const float* __restrict__ kb,  const float* __restrict__ ks_,
                         const float* __restrict__ vb,  const float* __restrict__ vs,
                         const float* __restrict__ ob,  const float* __restrict__ os_,
                         half_t* __restrict__ W1hi, half_t* __restrict__ W1lo,
                         half_t* __restrict__ W2hi, half_t* __restrict__ W2lo,
                         half_t* __restrict__ Wqhi, half_t* __restrict__ Wohi) {
    int idx = blockIdx.x * 256 + threadIdx.x;   // 0 .. 2097152
    const float* base; const float* spline; half_t* Whi; half_t* Wlo; int IN; int li;
    if (idx < 524288)       { base = k1b; spline = k1s; Whi = W1hi; Wlo = W1lo; IN = 512;  li = idx; }
    else if (idx < 1048576) { base = k2b; spline = k2s; Whi = W2hi; Wlo = W2lo; IN = 1024; li = idx - 524288; }
    else if (idx < 1310720) { base = qb;  spline = qs;  Whi = Wqhi;                      Wlo = nullptr; IN = 512; li = idx - 1048576; }
    else if (idx < 1572864) { base = kb;  spline = ks_; Whi = Wqhi + (size_t)512 * 4608; Wlo = nullptr; IN = 512; li = idx - 1310720; }
    else if (idx < 1835008) { base = vb;  spline = vs;  Whi = Wqhi + (size_t)1024 * 4608; Wlo = nullptr; IN = 512; li = idx - 1572864; }
    else                    { base = ob;  spline = os_; Whi = Wohi; Wlo = nullptr; IN = 512; li = idx - 1835008; }
    int o = li / IN, i = li % IN;
    long r0 = (long)o * 9 * IN + i;
    long widx = (long)o * IN + i;
    float w[9];
    w[0] = base[widx];
    const f32x4* sp = (const f32x4*)(spline + widx * 8);
    f32x4 s0 = sp[0], s1 = sp[1];
    w[1] = s0[0]; w[2] = s0[1]; w[3] = s0[2]; w[4] = s0[3];
    w[5] = s1[0]; w[6] = s1[1]; w[7] = s1[2]; w[8] = s1[3];
    #pragma unroll
    for (int c = 0; c < 9; ++c) {
        half_t hi = (half_t)w[c];
        Whi[r0 + (long)c * IN] = hi;
        if (Wlo) Wlo[r0 + (long)c * IN] = (half_t)(w[c] - (float)hi);
    }
}

enum { EPI_PART = 0, EPI_QKV = 1, EPI_RELU = 4 };

// ---------------- weight GEMM: 2-barrier structure, multi-B amortization (r19-proven) ----------------
// 128x(128*NB) tile, 4 waves (2x2), BK=64. Per K-tile stage A ONCE + NPASS*NB B-tiles
// (hi/lo passes and/or adjacent N-stripes) -> NPASS*NB*16 MFMA per barrier-pair.
// Swizzle chunk^(row&7) on global source AND ds_read (conflict-free, r7/r13-verified).
// KSPLIT>1 slices real K-tiles across blockIdx.z (each slice does all passes) -> fp32 P[z].
template<int EPI, int NPASS, int KSPLIT, int NB, int MINW>
__global__ __launch_bounds__(256, MINW)
void gemm_w(const ushort_t* __restrict__ A, const ushort_t* __restrict__ Bhi,
            const ushort_t* __restrict__ Blo, float* __restrict__ Cf, float* __restrict__ P,
            half_t* __restrict__ Qp, half_t* __restrict__ Kp, half_t* __restrict__ Vp,
            int M, int N, int K) {
    __shared__ __attribute__((aligned(16))) ushort_t As[128 * 64];
    __shared__ __attribute__((aligned(16))) ushort_t Bs[NPASS * NB][128 * 64];
    const int tid = threadIdx.x;
    const int lane = tid & 63;
    const int wave = tid >> 6;
    const int wm = wave >> 1, wn = wave & 1;
    const int bm = blockIdx.x * 128, bn = blockIdx.y * (128 * NB);
    const int l15 = lane & 15, l16 = lane >> 4;
    const int NT = K >> 6;
    int kc, t0;
    if constexpr (KSPLIT > 1) { kc = NT / KSPLIT; t0 = blockIdx.z * kc; }
    else { kc = NT; t0 = 0; }

    f32x4 acc[4][4 * NB];
    #pragma unroll
    for (int m = 0; m < 4; ++m)
        #pragma unroll
        for (int n = 0; n < 4 * NB; ++n) acc[m][n] = (f32x4){0.f, 0.f, 0.f, 0.f};

    for (int u = 0; u < kc; ++u) {
        int kt = (t0 + u) << 6;
        #pragma unroll
        for (int r = 0; r < 4; ++r) {
            int ch = r * 256 + tid;             // A: 1024 chunks of 8 halves per 128x64 tile
            int row = ch >> 3, c = ch & 7;
            gld_lds16(A + (long)(bm + row) * K + kt + ((c ^ (row & 7)) << 3), &As[ch * 8]);
        }
        #pragma unroll
        for (int q = 0; q < NPASS * NB; ++q) {
            const ushort_t* Bb = (q >= NB) ? Blo : Bhi;
            int bcol = bn + (q % NB) * 128;
            #pragma unroll
            for (int r = 0; r < 4; ++r) {
                int ch = r * 256 + tid;
                int row = ch >> 3, c = ch & 7;
                gld_lds16(Bb + (long)(bcol + row) * K + kt + ((c ^ (row & 7)) << 3), &Bs[q][ch * 8]);
            }
        }
        __syncthreads();
        #pragma unroll
        for (int q = 0; q < NPASS * NB; ++q) {
            const int nb = q % NB;
            #pragma unroll
            for (int kk = 0; kk < 2; ++kk) {
                half8 af[4], bfr[4];
                #pragma unroll
                for (int m = 0; m < 4; ++m) {
                    int row = wm * 64 + m * 16 + l15;
                    af[m] = __builtin_bit_cast(half8, *(const short8*)&As[row * 64 + (((kk * 4 + l16) ^ (row & 7)) << 3)]);
                }
                #pragma unroll
                for (int n = 0; n < 4; ++n) {
                    int row = wn * 64 + n * 16 + l15;
                    bfr[n] = __builtin_bit_cast(half8, *(const short8*)&Bs[q][row * 64 + (((kk * 4 + l16) ^ (row & 7)) << 3)]);
                }
                #pragma unroll
                for (int m = 0; m < 4; ++m)
                    #pragma unroll
                    for (int n = 0; n < 4; ++n)
                        acc[m][nb * 4 + n] = __builtin_amdgcn_mfma_f32_16x16x32_f16(af[m], bfr[n], acc[m][nb * 4 + n], 0, 0, 0);
            }
        }
        __syncthreads();
    }

    // epilogue: C/D layout col=lane&15, row=(lane>>4)*4+j (m89-verified)
    #pragma unroll
    for (int nb = 0; nb < NB; ++nb) {
        #pragma unroll
        for (int m = 0; m < 4; ++m) {
            #pragma unroll
            for (int n = 0; n < 4; ++n) {
                #pragma unroll
                for (int j = 0; j < 4; ++j) {
                    int row = bm + wm * 64 + m * 16 + l16 * 4 + j;
                    int col = bn + nb * 128 + wn * 64 + n * 16 + l15;
                    float v = acc[m][nb * 4 + n][j];
                    if constexpr (KSPLIT > 1) {
                        P[(size_t)blockIdx.z * M * N + (long)row * N + col] = v;
                    } else if constexpr (EPI == EPI_RELU) {
                        Cf[(long)row * N + col] = fmaxf(v, 0.0f);
                    } else if constexpr (EPI == EPI_QKV) {
                        int which = col >> 9, w5 = col & 511, h = w5 >> 7, d = w5 & 127;
                        int b = row >> 10, ss = row & 1023;
                        half_t* dst = (which == 0) ? Qp : ((which == 1) ? Kp : Vp);
                        dst[(((long)(b * 4 + h) * 1024 + ss) << 7) + d] = (half_t)v;
                    }
                }
            }
        }
    }
}

// ---------------- fused flash attention (r16-proven): writes AO fp32 coalesced ----------------
__global__ __launch_bounds__(256, 1)
void flash_attn(const ushort_t* __restrict__ Q, const ushort_t* __restrict__ Kb,
                const ushort_t* __restrict__ Vt, float* __restrict__ AO, float scale) {
    constexpr int TS = 128 * 128;
    __shared__ __attribute__((aligned(16))) ushort_t Qs[TS];
    __shared__ __attribute__((aligned(16))) ushort_t Ks[TS];
    __shared__ __attribute__((aligned(16))) ushort_t Vs[TS];
    __shared__ __attribute__((aligned(16))) half_t  Ps[TS];
    const int tid = threadIdx.x;
    const int lane = tid & 63;
    const int w = tid >> 6;
    const int l15 = lane & 15, l16 = lane >> 4;
    const int bm = blockIdx.x * 128;
    const int bh = blockIdx.y;
    const ushort_t* Qg = Q + (long)bh * 1024 * 128;
    const ushort_t* Kg = Kb + (long)bh * 1024 * 128;
    const ushort_t* Vg = Vt + (long)bh * 128 * 1024;

    #pragma unroll
    for (int r = 0; r < 8; ++r) {
        int ch = r * 256 + tid;
        int row = ch >> 4, c = ch & 15;
        gld_lds16(Qg + (long)(bm + row) * 128 + ((c ^ (row & 15)) << 3), &Qs[ch * 8]);
    }
    __syncthreads();
    half8 qf[2][4];
    #pragma unroll
    for (int mf = 0; mf < 2; ++mf)
        #pragma unroll
        for (int kk = 0; kk < 4; ++kk) {
            int row = w * 32 + mf * 16 + l15;
            qf[mf][kk] = __builtin_bit_cast(half8, *(const short8*)&Qs[row * 128 + (((kk * 4 + l16) ^ (row & 15)) << 3)]);
        }

    f32x4 o_acc[2][8];
    #pragma unroll
    for (int mf = 0; mf < 2; ++mf)
        #pragma unroll
        for (int nf = 0; nf < 8; ++nf) o_acc[mf][nf] = (f32x4){0.f, 0.f, 0.f, 0.f};
    float m_run[2][4], l_run[2][4];
    #pragma unroll
    for (int mf = 0; mf < 2; ++mf)
        #pragma unroll
        for (int j = 0; j < 4; ++j) { m_run[mf][j] = -3.0e38f; l_run[mf][j] = 0.f; }

    for (int t = 0; t < 8; ++t) {
        int kv0 = t * 128;
        #pragma unroll
        for (int r = 0; r < 8; ++r) {
            int ch = r * 256 + tid;
            int row = ch >> 4, c = ch & 15;
            gld_lds16(Kg + (long)(kv0 + row) * 128 + ((c ^ (row & 15)) << 3), &Ks[ch * 8]);
        }
        #pragma unroll
        for (int r = 0; r < 8; ++r) {
            int ch = r * 256 + tid;
            int row = ch >> 4, c = ch & 15;
            gld_lds16(Vg + (long)row * 1024 + kv0 + ((c ^ (row & 15)) << 3), (ushort_t*)&Vs[ch * 8]);
        }
        __syncthreads();
        f32x4 s_acc[2][8];
        #pragma unroll
        for (int mf = 0; mf < 2; ++mf)
            #pragma unroll
            for (int nf = 0; nf < 8; ++nf) s_acc[mf][nf] = (f32x4){0.f, 0.f, 0.f, 0.f};
        #pragma unroll
        for (int nf = 0; nf < 8; ++nf) {
            #pragma unroll
            for (int kk = 0; kk < 4; ++kk) {
                int row = nf * 16 + l15;
                half8 bf = __builtin_bit_cast(half8, *(const short8*)&Ks[row * 128 + (((kk * 4 + l16) ^ (row & 15)) << 3)]);
                #pragma unroll
                for (int mf = 0; mf < 2; ++mf)
                    s_acc[mf][nf] = __builtin_amdgcn_mfma_f32_16x16x32_f16(qf[mf][kk], bf, s_acc[mf][nf], 0, 0, 0);
            }
        }
        #pragma unroll
        for (int mf = 0; mf < 2; ++mf) {
            #pragma unroll
            for (int j = 0; j < 4; ++j) {
                float rmax = -3.0e38f;
                #pragma unroll
                for (int nf = 0; nf < 8; ++nf) rmax = fmaxf(rmax, s_acc[mf][nf][j]);
                #pragma unroll
                for (int off = 1; off < 16; off <<= 1) rmax = fmaxf(rmax, __shfl_xor(rmax, off));
                float m_new = fmaxf(m_run[mf][j], rmax * scale);
                float alpha = __expf(m_run[mf][j] - m_new);
                m_run[mf][j] = m_new;
                float rsum = 0.f;
                #pragma unroll
                for (int nf = 0; nf < 8; ++nf) {
                    float pv = __expf(s_acc[mf][nf][j] * scale - m_new);
                    s_acc[mf][nf][j] = pv;
                    rsum += pv;
                }
                #pragma unroll
                for (int off = 1; off < 16; off <<= 1) rsum += __shfl_xor(rsum, off);
                l_run[mf][j] = l_run[mf][j] * alpha + rsum;
                #pragma unroll
                for (int nf = 0; nf < 8; ++nf) o_acc[mf][nf][j] *= alpha;
            }
        }
        #pragma unroll
        for (int mf = 0; mf < 2; ++mf)
            #pragma unroll
            for (int nf = 0; nf < 8; ++nf)
                #pragma unroll
                for (int j = 0; j < 4; ++j) {
                    int row = w * 32 + mf * 16 + l16 * 4 + j;
                    int col = nf * 16 + l15;
                    int sch = (col >> 3) ^ (row & 15);
                    Ps[row * 128 + (sch << 3) + (col & 7)] = (half_t)s_acc[mf][nf][j];
                }
        __syncthreads();
        half8 pf[2][4];
        #pragma unroll
        for (int mf = 0; mf < 2; ++mf)
            #pragma unroll
            for (int kk = 0; kk < 4; ++kk) {
                int row = w * 32 + mf * 16 + l15;
                pf[mf][kk] = __builtin_bit_cast(half8, *(const short8*)&Ps[row * 128 + (((kk * 4 + l16) ^ (row & 15)) << 3)]);
            }
        #pragma unroll
        for (int nf = 0; nf < 8; ++nf) {
            #pragma unroll
            for (int kk = 0; kk < 4; ++kk) {
                int row = nf * 16 + l15;
                half8 bf = __builtin_bit_cast(half8, *(const short8*)&Vs[row * 128 + (((kk * 4 + l16) ^ (row & 15)) << 3)]);
                #pragma unroll
                for (int mf = 0; mf < 2; ++mf)
                    o_acc[mf][nf] = __builtin_amdgcn_mfma_f32_16x16x32_f16(pf[mf][kk], bf, o_acc[mf][nf], 0, 0, 0);
            }
        }
        __syncthreads();
    }
    int b = bh >> 2, h = bh & 3;
    #pragma unroll
    for (int mf = 0; mf < 2; ++mf) {
        #pragma unroll
        for (int nf = 0; nf < 8; ++nf) {
            #pragma unroll
            for (int j = 0; j < 4; ++j) {
                int row = bm + w * 32 + mf * 16 + l16 * 4 + j;
                int col = nf * 16 + l15;
                AO[(long)(b * 1024 + row) * 512 + h * 128 + col] = o_acc[mf][nf][j] / l_run[mf][j];
            }
        }
    }
}

// ---------------- split-K reduction ----------------
template<int KS, bool RELU>
__global__ void reduce_kernel(const float* __restrict__ P, float* __restrict__ out, long MN) {
    long i = ((long)blockIdx.x * 256 + threadIdx.x) * 4;
    if (i >= MN) return;
    f32x4 s = *(const f32x4*)&P[i];
    #pragma unroll
    for (int zz = 1; zz < KS; ++zz) {
        f32x4 t = *(const f32x4*)&P[(size_t)zz * MN + i];
        s += t;
    }
    if constexpr (RELU) {
        s[0] = fmaxf(s[0], 0.f); s[1] = fmaxf(s[1], 0.f);
        s[2] = fmaxf(s[2], 0.f); s[3] = fmaxf(s[3], 0.f);
    }
    *(f32x4*)&out[i] = s;
}

// ---------------- V transpose ----------------
__global__ void transpose_v(const ushort_t* __restrict__ V, ushort_t* __restrict__ Vt) {
    __shared__ ushort_t t[64][72];
    int s0 = blockIdx.x * 64, d0 = blockIdx.y * 64, bh = blockIdx.z;
    const ushort_t* Vb = V + (long)bh * 1024 * 128;
    ushort_t* Vtb = Vt + (long)bh * 128 * 1024;
    int tid = threadIdx.x;
    int r = tid >> 2, g = tid & 3;
    #pragma unroll
    for (int j = 0; j < 16; ++j)
        t[r][g * 16 + j] = Vb[(long)(s0 + r) * 128 + d0 + g * 16 + j];
    __syncthreads();
    #pragma unroll
    for (int j = 0; j < 16; ++j)
        Vtb[(long)(d0 + r) * 1024 + s0 + g * 16 + j] = t[g * 16 + j][r];
}

// ---------------- fused split-K2 reduce + residual + LayerNorm (rows of 512) ----------------
__global__ void reduce2_ln_kernel(const float* __restrict__ P, long MN,
                                  const float* __restrict__ X,
                                  const float* __restrict__ g, const float* __restrict__ b,
                                  float* __restrict__ out) {
    long row = (long)blockIdx.x * 4 + (threadIdx.x >> 6);
    int lane = threadIdx.x & 63;
    long base = row * 512 + lane * 8;
    f32x4 p0 = *(const f32x4*)&P[base],      p1 = *(const f32x4*)&P[base + 4];
    f32x4 q0 = *(const f32x4*)&P[MN + base], q1 = *(const f32x4*)&P[MN + base + 4];
    f32x4 x0 = *(const f32x4*)&X[base],      x1 = *(const f32x4*)&X[base + 4];
    float y[8];
    #pragma unroll
    for (int j = 0; j < 4; ++j) {
        y[j]     = (p0[j] + q0[j]) + x0[j];
        y[j + 4] = (p1[j] + q1[j]) + x1[j];
    }
    float s = 0.f;
    #pragma unroll
    for (int j = 0; j < 8; ++j) s += y[j];
    #pragma unroll
    for (int off = 32; off > 0; off >>= 1) s += __shfl_xor(s, off);
    float mu = s * (1.0f / 512.0f);
    float vs = 0.f;
    #pragma unroll
    for (int j = 0; j < 8; ++j) { float d = y[j] - mu; vs += d * d; }
    #pragma unroll
    for (int off = 32; off > 0; off >>= 1) vs += __shfl_xor(vs, off);
    float r = rsqrtf(vs * (1.0f / 512.0f) + 1e-5f);
    f32x4 w0 = *(const f32x4*)&g[lane * 8], w1 = *(const f32x4*)&g[lane * 8 + 4];
    f32x4 b0 = *(const f32x4*)&b[lane * 8], b1 = *(const f32x4*)&b[lane * 8 + 4];
    f32x4 r0, r1;
    #pragma unroll
    for (int j = 0; j < 4; ++j) {
        r0[j] = (y[j] - mu) * r * w0[j] + b0[j];
        r1[j] = (y[j + 4] - mu) * r * w1[j] + b1[j];
    }
    *(f32x4*)&out[base] = r0;
    *(f32x4*)&out[base + 4] = r1;
}

// ---------------- launch ----------------
extern "C" void kernel_launch(void* const* d_in, const int* in_sizes, int n_in,
                              void* d_out, int out_size, void* d_ws, size_t ws_size,
                              hipStream_t stream) {
    const float* x         = (const float*)d_in[0];
    const float* k1_base   = (const float*)d_in[1];
    const float* k1_spline = (const float*)d_in[2];
    const float* k2_base   = (const float*)d_in[3];
    const float* k2_spline = (const float*)d_in[4];
    const float* q_base    = (const float*)d_in[5];
    const float* q_spline  = (const float*)d_in[6];
    const float* k_base    = (const float*)d_in[7];
    const float* k_spline  = (const float*)d_in[8];
    const float* v_base    = (const float*)d_in[9];
    const float* v_spline  = (const float*)d_in[10];
    const float* o_base    = (const float*)d_in[11];
    const float* o_spline  = (const float*)d_in[12];
    const float* ln_w      = (const float*)d_in[13];
    const float* ln_b      = (const float*)d_in[14];
    float* out = (float*)d_out;

    constexpr int Dm = 512, HD = 1024, NR = 8192;
    constexpr int K1 = 9 * Dm;   // 4608
    constexpr int K2 = 9 * HD;   // 9216
    constexpr size_t MB = 1024 * 1024;

    char* p = (char*)d_ws;
    size_t off = 0;
    auto take = [&](size_t bytes) -> char* {
        char* r = p + off;
        off += (bytes + 255) & ~(size_t)255;
        return r;
    };
    half_t* W1hi = (half_t*)take((size_t)HD * K1 * 2);        //  9 MB
    half_t* W2hi = (half_t*)take((size_t)Dm * K2 * 2);        //  9 MB
    half_t* Wqhi = (half_t*)take((size_t)3 * Dm * K1 * 2);    // 13.5 MB
    half_t* Wohi = (half_t*)take((size_t)Dm * K1 * 2);        //  4.5 MB
    half_t* W1lo = (half_t*)take((size_t)HD * K1 * 2);
    half_t* W2lo = (half_t*)take((size_t)Dm * K2 * 2);
    char*   A    = take((size_t)152 * MB);                    // total 206 MB (< 224 proven-safe)
    (void)ws_size; (void)in_sizes; (void)n_in; (void)out_size;

    // arena phase map (MB):
    // A: E1 @0..72 | H1 fp32 @72..104 (direct ReLU epilogue)
    // B: E2c @0..72 | H1 @72..104 | P2 @104..136 (4x8) | H2 @136..152
    // C: E3 @0..72 | Q @72..80 K @80..88 V @88..96 | H2 @136..152
    // D: Vt @96..104 (V dead) | flash: reads Q/K/Vt, writes AO fp32 @104..120
    // E: E4 @0..72 (E3 dead) | P3 @120..152 (2x16) | fused reduce2+LN reads P3
    half_t* E1   = (half_t*)(A);
    float*  H1   = (float*)(A + 72 * MB);
    half_t* E2   = (half_t*)(A);
    float*  P2   = (float*)(A + 104 * MB);
    float*  H2   = (float*)(A + 136 * MB);
    half_t* E3   = (half_t*)(A);
    half_t* Qb   = (half_t*)(A + 72 * MB);
    half_t* Kb   = (half_t*)(A + 80 * MB);
    half_t* Vb   = (half_t*)(A + 88 * MB);
    half_t* Vt   = (half_t*)(A + 96 * MB);
    float*  AO   = (float*)(A + 104 * MB);
    half_t* E4   = (half_t*)(A);
    float*  P3   = (float*)(A + 120 * MB);

    // single fused pack launch; q/k/v/o layers are hi-only
    pack_all<<<2097152 / 256, 256, 0, stream>>>(
        k1_base, k1_spline, k2_base, k2_spline, q_base, q_spline,
        k_base, k_spline, v_base, v_spline, o_base, o_spline,
        W1hi, W1lo, W2hi, W2lo, Wqhi, Wohi);

    // KAN1: hi+lo fused per K-tile (A staged once), direct ReLU epilogue, grid 64x8 = 512
    expand_kernel<Dm><<<(NR * Dm) / 256, 256, 0, stream>>>(x, E1, NR);
    gemm_w<EPI_RELU, 2, 1, 1, 4><<<dim3(NR / 128, HD / 128, 1), 256, 0, stream>>>(
        (const ushort_t*)E1, (const ushort_t*)W1hi, (const ushort_t*)W1lo,
        H1, nullptr, nullptr, nullptr, nullptr, NR, HD, K1);

    // KAN2 (2 M-chunks, hi+lo fused, KSPLIT=4 over real tiles): grid 32x4x4 = 512
    for (int c = 0; c < 2; ++c) {
        expand_kernel<HD><<<(4096 * HD) / 256, 256, 0, stream>>>(H1 + (size_t)c * 4096 * HD, E2, 4096);
        gemm_w<EPI_PART, 2, 4, 1, 4><<<dim3(4096 / 128, Dm / 128, 4), 256, 0, stream>>>(
            (const ushort_t*)E2, (const ushort_t*)W2hi, (const ushort_t*)W2lo,
            nullptr, P2, nullptr, nullptr, nullptr, 4096, Dm, K2);
        reduce_kernel<4, false><<<(4096 * Dm) / 1024, 256, 0, stream>>>(P2, H2 + (size_t)c * 4096 * Dm, (long)4096 * Dm);
    }

    // QKV: hi-only, NB=2 (A staged once per 256-col stripe), grid 64x6 = 384
    expand_kernel<Dm><<<(NR * Dm) / 256, 256, 0, stream>>>(H2, E3, NR);
    gemm_w<EPI_QKV, 1, 1, 2, 2><<<dim3(NR / 128, (3 * Dm) / 256, 1), 256, 0, stream>>>(
        (const ushort_t*)E3, (const ushort_t*)Wqhi, nullptr,
        nullptr, nullptr, Qb, Kb, Vb, NR, 3 * Dm, K1);

    // attention: Vt transpose; fused flash -> AO (coalesced), grid 8x32 = 256
    transpose_v<<<dim3(16, 2, 32), 256, 0, stream>>>((const ushort_t*)Vb, (ushort_t*)Vt);
    flash_attn<<<dim3(8, 32), 256, 0, stream>>>(
        (const ushort_t*)Qb, (const ushort_t*)Kb, (const ushort_t*)Vt, AO,
        0.08838834764831845f);

    // O-proj: E4 = expand(AO); hi-only, NB=2, KSPLIT=2, grid 64x2x2 = 256; fused reduce2+res+LN
    expand_kernel<Dm><<<(NR * Dm) / 256, 256, 0, stream>>>(AO, E4, NR);
    gemm_w<EPI_PART, 1, 2, 2, 2><<<dim3(NR / 128, Dm / 256, 2), 256, 0, stream>>>(
        (const ushort_t*)E4, (const ushort_t*)Wohi, nullptr,
        nullptr, P3, nullptr, nullptr, nullptr, NR, Dm, K1);
    reduce2_ln_kernel<<<NR / 4, 256, 0, stream>>>(P3, (long)NR * Dm, x, ln_w, ln_b, out);
}